// Round 16
// baseline (408.418 us; speedup 1.0000x reference)
//
#include <hip/hip_runtime.h>

#define NNODE 6144
#define FEATD 512
#define HIDD  512
#define NCLSD 64
#define NMSK  (NNODE/64)   // 96 mask words per row
#define NKT   (NNODE/32)   // 192 k-tiles (node dim)
#define NKTX  (FEATD/32)   // 16 k-tiles (feature dim)
#define LALPHA 0.2f

typedef unsigned short ushort_t;
typedef unsigned int uint_t;
typedef unsigned long long u64_t;
typedef short bf16x8 __attribute__((ext_vector_type(8)));
typedef float f32x4 __attribute__((ext_vector_type(4)));

__device__ __forceinline__ float lrelu(float x){ return x > 0.f ? x : LALPHA * x; }

__device__ __forceinline__ ushort_t f2b(float x){
    union { float f; unsigned u; } v; v.f = x;
    unsigned r = v.u + 0x7fffu + ((v.u >> 16) & 1u);
    return (ushort_t)(r >> 16);
}
__device__ __forceinline__ float b2f(ushort_t u){
    union { unsigned u; float f; } v; v.u = ((unsigned)u) << 16; return v.f;
}
// order-preserving float<->uint encoding (memset-0 == -inf identity for max)
__device__ __forceinline__ uint_t encf(float f){
    uint_t u = __float_as_uint(f);
    return (u & 0x80000000u) ? ~u : (u | 0x80000000u);
}
__device__ __forceinline__ float decf(uint_t k){
    uint_t u = (k & 0x80000000u) ? (k & 0x7FFFFFFFu) : ~k;
    return __uint_as_float(u);
}

// Runtime C/D-layout calibration (round-8 validated)
__device__ __forceinline__ void calib_cd(int lm, int* qrow, int* vcol){
    bf16x8 ai, as;
    ushort_t vi = f2b((float)(lm + 1));
    ushort_t vs = f2b(0.03125f);
    #pragma unroll
    for (int e = 0; e < 8; e++){ ((ushort_t*)&ai)[e] = vi; ((ushort_t*)&as)[e] = vs; }
    f32x4 z = {0.f, 0.f, 0.f, 0.f};
    f32x4 d1 = __builtin_amdgcn_mfma_f32_16x16x32_bf16(ai, as, z, 0, 0, 0);
    f32x4 d2 = __builtin_amdgcn_mfma_f32_16x16x32_bf16(as, ai, z, 0, 0, 0);
    #pragma unroll
    for (int r = 0; r < 4; r++){
        qrow[r] = (int)(d1[r] + 0.5f) - 1;
        vcol[r] = (int)(d2[r] + 0.5f) - 1;
    }
}

// ---------------- adj (int32) -> bitmask ----------------
__global__ void k_adjmask(const int* __restrict__ adj, u64_t* __restrict__ mask){
    int lane = threadIdx.x & 63;
    size_t wid = ((size_t)blockIdx.x * blockDim.x + threadIdx.x) >> 6;
    size_t nw = (size_t)NNODE * NNODE / 64;
    size_t stride = ((size_t)gridDim.x * blockDim.x) >> 6;
    for (size_t q = wid; q < nw; q += stride){
        int a = adj[q * 64 + lane];
        u64_t b = __ballot(a > 0);
        if (lane == 0) mask[q] = b;
    }
}

// out1[r]=W[r]·a[0:K]; out2[r]=W[r]·a[K:2K]  (one wave per row)
__global__ void k_fold(const float* __restrict__ W, const float* __restrict__ a,
                       float* __restrict__ out1, float* __restrict__ out2, int K){
    int row  = (blockIdx.x * blockDim.x + threadIdx.x) >> 6;
    int lane = threadIdx.x & 63;
    const float* wr = W + (size_t)row * K;
    float s1 = 0.f, s2 = 0.f;
    for (int c = lane; c < K; c += 64){ float w = wr[c]; s1 += w * a[c]; s2 += w * a[K + c]; }
    #pragma unroll
    for (int m = 32; m; m >>= 1){ s1 += __shfl_xor(s1, m); s2 += __shfl_xor(s2, m); }
    if (lane == 0){ out1[row] = s1; out2[row] = s2; }
}

// ---------------- o1/o2 = A @ {v1,v2} + encoded max(o2) ----------------
__global__ void k_rowvec2_max(const float* __restrict__ A, const float* __restrict__ v1,
                              const float* __restrict__ v2, float* __restrict__ o1,
                              float* __restrict__ o2, uint_t* __restrict__ mEnc, int K){
    int row  = (blockIdx.x * blockDim.x + threadIdx.x) >> 6;
    int lane = threadIdx.x & 63;
    const float* r = A + (size_t)row * K;
    float s1 = 0.f, s2 = 0.f;
    for (int c = lane; c < K; c += 64){ float x = r[c]; s1 += x * v1[c]; s2 += x * v2[c]; }
    #pragma unroll
    for (int m = 32; m; m >>= 1){ s1 += __shfl_xor(s1, m); s2 += __shfl_xor(s2, m); }
    if (lane == 0){ o1[row] = s1; o2[row] = s2; atomicMax(mEnc, encf(s2)); }
}

// ---------------- dst[c*R + r] = bf16(src[r*C + c]) ----------------
__global__ void k_transpose_bf16(const float* __restrict__ src, ushort_t* __restrict__ dst,
                                 int R, int C){
    int idx = blockIdx.x * blockDim.x + threadIdx.x;
    if (idx >= R * C) return;
    int r = idx / C, c = idx - r * C;
    dst[(size_t)c * R + r] = f2b(src[idx]);
}

// ---------------- fused: X -> XF fragments + e1/e2 scores + e2max ----------------
__global__ __launch_bounds__(256) void k_xprep(const float* __restrict__ X,
        const float* __restrict__ wg1, const float* __restrict__ wg2,
        ushort_t* __restrict__ XF, float* __restrict__ e1, float* __restrict__ e2,
        uint_t* __restrict__ e2mE){
    __shared__ float w1s[FEATD], w2s[FEATD];
    int ri = blockIdx.x;
    int tid = threadIdx.x;
    int r = tid >> 4, q = tid & 15;
    for (int k = tid; k < FEATD; k += 256){ w1s[k] = wg1[k]; w2s[k] = wg2[k]; }
    __syncthreads();
    const float* xp = X + (size_t)(ri * 16 + r) * FEATD;
    ushort_t* xb = XF + (size_t)ri * NKTX * 512;
    float s1 = 0.f, s2 = 0.f;
    for (int j0 = 0; j0 < FEATD; j0 += 128){
        int j = j0 + q * 8;
        float4 fA = *(const float4*)(xp + j);
        float4 fB = *(const float4*)(xp + j + 4);
        float xa[8] = {fA.x, fA.y, fA.z, fA.w, fB.x, fB.y, fB.z, fB.w};
        bf16x8 pk;
        #pragma unroll
        for (int e = 0; e < 8; e++){
            ((ushort_t*)&pk)[e] = f2b(xa[e]);
            s1 += xa[e] * w1s[j + e];
            s2 += xa[e] * w2s[j + e];
        }
        int ki = j >> 5;
        int lh = (j >> 3) & 3;
        *(bf16x8*)(xb + ((size_t)ki * 512 + (size_t)(r + (lh << 4)) * 8)) = pk;
    }
    #pragma unroll
    for (int o = 8; o; o >>= 1){ s1 += __shfl_xor(s1, o); s2 += __shfl_xor(s2, o); }
    if (q == 0){
        int row = ri * 16 + r;
        e1[row] = s1; e2[row] = s2;
        atomicMax(e2mE, encf(s2));
    }
}

// ---------------- Wg -> WgF fragment layout (B-operand) ----------------
__global__ __launch_bounds__(256) void k_wgfrag(const float* __restrict__ Wg,
                                                ushort_t* __restrict__ WgF){
    int gid = blockIdx.x * 256 + threadIdx.x;
    if (gid >= (HIDD/16) * NKTX * 64) return;
    int l = gid & 63, unit = gid >> 6;
    int ci = unit / NKTX, ki = unit - ci * NKTX;
    int lm = l & 15, lh = l >> 4;
    bf16x8 pk;
    #pragma unroll
    for (int e = 0; e < 8; e++)
        ((ushort_t*)&pk)[e] = f2b(Wg[(size_t)(ki*32 + lh*8 + e) * HIDD + ci*16 + lm]);
    *(bf16x8*)(WgF + (size_t)unit * 512 + (size_t)l * 8) = pk;
}

// ---------------- Wh1 = X @ Wg via MFMA -> VF fragments ----------------
__global__ __launch_bounds__(512) void k_gemm_xw(const ushort_t* __restrict__ XF,
        const ushort_t* __restrict__ WgF, ushort_t* __restrict__ VF){
    int ri = blockIdx.x;
    int i0 = ri * 16;
    int w = threadIdx.x >> 6, l = threadIdx.x & 63, lm = l & 15;
    int c0 = w * 64;
    int qrow[4], vcol[4];
    calib_cd(lm, qrow, vcol);
    f32x4 acc[4] = {};
    const ushort_t* Ap = XF + (size_t)ri * NKTX * 512 + l * 8;
    const ushort_t* Bp[4];
    #pragma unroll
    for (int t = 0; t < 4; t++)
        Bp[t] = WgF + (size_t)((c0 >> 4) + t) * NKTX * 512 + l * 8;
    for (int ki = 0; ki < NKTX; ki++){
        bf16x8 af = *(const bf16x8*)(Ap + (size_t)ki * 512);
        #pragma unroll
        for (int t = 0; t < 4; t++){
            bf16x8 bf = *(const bf16x8*)(Bp[t] + (size_t)ki * 512);
            acc[t] = __builtin_amdgcn_mfma_f32_16x16x32_bf16(af, bf, acc[t], 0, 0, 0);
        }
    }
    #pragma unroll
    for (int t = 0; t < 4; t++){
        int ci = (c0 >> 4) + t;
        #pragma unroll
        for (int r = 0; r < 4; r++){
            int node = i0 + qrow[r];
            size_t vo = ((size_t)ci * NKT + (node >> 5)) * 512
                      + (size_t)(vcol[r] + ((node >> 3) & 3) * 16) * 8 + (node & 7);
            VF[vo] = f2b(acc[t][r]);
        }
    }
}

// ---------------- Wh2 = res @ Wo via MFMA; emits VF2 + fused o1/o2/o2max ----------------
__global__ __launch_bounds__(256) void k_gemm_out(const float* __restrict__ res,
        const ushort_t* __restrict__ BT, const float* __restrict__ ao,
        ushort_t* __restrict__ VF2, float* __restrict__ o1v, float* __restrict__ o2v,
        uint_t* __restrict__ o2mE){
    __shared__ float o1s[64], o2s[64];
    int tid = threadIdx.x;
    int w = tid >> 6, l = tid & 63, lm = l & 15, lh = l >> 4;
    int i0 = blockIdx.x * 64 + w * 16;
    if (tid < 64){ o1s[tid] = 0.f; o2s[tid] = 0.f; }
    __syncthreads();
    int qrow[4], vcol[4];
    calib_cd(lm, qrow, vcol);
    f32x4 acc[4] = {};
    const float* ap = res + (size_t)(i0 + lm) * HIDD + lh * 8;
    for (int k0 = 0; k0 < HIDD; k0 += 32){
        float4 x0 = *(const float4*)(ap + k0);
        float4 x1 = *(const float4*)(ap + k0 + 4);
        float xa[8] = {x0.x, x0.y, x0.z, x0.w, x1.x, x1.y, x1.z, x1.w};
        bf16x8 af;
        #pragma unroll
        for (int e = 0; e < 8; e++) ((ushort_t*)&af)[e] = f2b(xa[e]);
        #pragma unroll
        for (int t = 0; t < 4; t++){
            bf16x8 bf = *(const bf16x8*)(BT + (size_t)(t*16 + lm) * HIDD + k0 + lh * 8);
            acc[t] = __builtin_amdgcn_mfma_f32_16x16x32_bf16(af, bf, acc[t], 0, 0, 0);
        }
    }
    #pragma unroll
    for (int r = 0; r < 4; r++){
        int node = i0 + qrow[r];
        float s1 = 0.f, s2 = 0.f;
        #pragma unroll
        for (int t = 0; t < 4; t++){
            int col = t*16 + vcol[r];
            float v = acc[t][r];
            size_t vo = ((size_t)t * NKT + (node >> 5)) * 512
                      + (size_t)(vcol[r] + ((node >> 3) & 3) * 16) * 8 + (node & 7);
            VF2[vo] = f2b(v);
            s1 += v * ao[col];
            s2 += v * ao[64 + col];
        }
        atomicAdd(&o1s[w*16 + qrow[r]], s1);
        atomicAdd(&o2s[w*16 + qrow[r]], s2);
    }
    __syncthreads();
    if (tid < 64){
        int row = blockIdx.x * 64 + tid;
        float v2 = o2s[tid];
        o1v[row] = o1s[tid];
        o2v[row] = v2;
        atomicMax(o2mE, encf(v2));
    }
}

// ---------------- P-gen: fragment layout PF + exact fp32 row sums ----------------
__global__ __launch_bounds__(256) void k_pgen(const u64_t* __restrict__ mask,
        const float* __restrict__ e1, const float* __restrict__ e2,
        const uint_t* __restrict__ e2mE, ushort_t* __restrict__ PF, float* __restrict__ lsum){
    __shared__ float e2s[NNODE];
    __shared__ u64_t msk[16][NMSK + 1];
    int ri = blockIdx.x;
    int i0 = ri * 16;
    int tid = threadIdx.x;
    int r = tid >> 4, q = tid & 15;
    for (int k = tid; k < NNODE; k += 256) e2s[k] = e2[k];
    for (int k = tid; k < 16 * NMSK; k += 256) msk[k / NMSK][k % NMSK] = mask[(size_t)i0 * NMSK + k];
    __syncthreads();
    float e1i = e1[i0 + r];
    float M = lrelu(e1i + decf(*e2mE));   // exact upper bound (softmax shift-invariant)
    float rsum = 0.f;
    ushort_t* pfb = PF + (size_t)ri * NKT * 512;
    for (int j0 = 0; j0 < NNODE; j0 += 128){
        int j = j0 + q * 8;
        u64_t word = msk[r][j >> 6];
        int sh = j & 63;
        float4 fA = *(const float4*)&e2s[j];
        float4 fB = *(const float4*)&e2s[j + 4];
        float ea[8] = {fA.x, fA.y, fA.z, fA.w, fB.x, fB.y, fB.z, fB.w};
        bf16x8 pk;
        #pragma unroll
        for (int e = 0; e < 8; e++){
            float p = ((word >> (sh + e)) & 1ull) ? __expf(lrelu(e1i + ea[e]) - M) : 0.f;
            ushort_t pb = f2b(p);
            ((ushort_t*)&pk)[e] = pb;
            rsum += b2f(pb);
        }
        int ki = j >> 5;
        int lh = (j >> 3) & 3;
        *(bf16x8*)(pfb + ((size_t)ki * 512 + (size_t)(r + (lh << 4)) * 8)) = pk;
    }
    #pragma unroll
    for (int o = 8; o; o >>= 1) rsum += __shfl_xor(rsum, o);
    if (q == 0) lsum[i0 + r] = rsum;
}

// ---------------- GAT1 GEMM v5: 32x64 wave tiles, banked 2x-unrolled loop ----------------
// grid 768: c8 = bid&7, rg = bid>>3 (96 groups of 64 rows); 128 thr = 2 waves.
__global__ __launch_bounds__(128) void k_gat1g(const ushort_t* __restrict__ PF,
        const float* __restrict__ lsum, const ushort_t* __restrict__ VF,
        float* __restrict__ res){
    int bid = blockIdx.x;
    int c8 = bid & 7, rg = bid >> 3;
    int tid = threadIdx.x;
    int w = tid >> 6, l = tid & 63, lm = l & 15;
    int ri0 = rg * 4 + w * 2, ri1 = ri0 + 1;
    int cbase = c8 * 64;
    int qrow[4], vcol[4];
    calib_cd(lm, qrow, vcol);
    f32x4 acc0[4] = {}, acc1[4] = {};
    const ushort_t* Ap0 = PF + (size_t)ri0 * NKT * 512 + l * 8;
    const ushort_t* Ap1 = PF + (size_t)ri1 * NKT * 512 + l * 8;
    const ushort_t* Vp[4];
    #pragma unroll
    for (int t = 0; t < 4; t++)
        Vp[t] = VF + (size_t)(c8 * 4 + t) * NKT * 512 + l * 8;
    bf16x8 a0A, a1A, vA[4], a0B, a1B, vB[4];
    a0A = *(const bf16x8*)(Ap0);
    a1A = *(const bf16x8*)(Ap1);
    #pragma unroll
    for (int t = 0; t < 4; t++) vA[t] = *(const bf16x8*)(Vp[t]);
    for (int kt = 0; kt < NKT; kt += 2){
        size_t ob = (size_t)(kt + 1) * 512;
        a0B = *(const bf16x8*)(Ap0 + ob);
        a1B = *(const bf16x8*)(Ap1 + ob);
        #pragma unroll
        for (int t = 0; t < 4; t++) vB[t] = *(const bf16x8*)(Vp[t] + ob);
        #pragma unroll
        for (int t = 0; t < 4; t++){
            acc0[t] = __builtin_amdgcn_mfma_f32_16x16x32_bf16(a0A, vA[t], acc0[t], 0, 0, 0);
            acc1[t] = __builtin_amdgcn_mfma_f32_16x16x32_bf16(a1A, vA[t], acc1[t], 0, 0, 0);
        }
        int k2 = (kt + 2 < NKT) ? kt + 2 : 0;
        size_t oa = (size_t)k2 * 512;
        a0A = *(const bf16x8*)(Ap0 + oa);
        a1A = *(const bf16x8*)(Ap1 + oa);
        #pragma unroll
        for (int t = 0; t < 4; t++) vA[t] = *(const bf16x8*)(Vp[t] + oa);
        #pragma unroll
        for (int t = 0; t < 4; t++){
            acc0[t] = __builtin_amdgcn_mfma_f32_16x16x32_bf16(a0B, vB[t], acc0[t], 0, 0, 0);
            acc1[t] = __builtin_amdgcn_mfma_f32_16x16x32_bf16(a1B, vB[t], acc1[t], 0, 0, 0);
        }
    }
    int i00 = ri0 * 16, i01 = ri1 * 16;
    #pragma unroll
    for (int r = 0; r < 4; r++){
        float den0 = lsum[i00 + qrow[r]];
        float den1 = lsum[i01 + qrow[r]];
        #pragma unroll
        for (int t = 0; t < 4; t++){
            int col = cbase + t*16 + vcol[r];
            float v0 = acc0[t][r] / den0;
            v0 = v0 > 0.f ? v0 : expm1f(v0);
            res[(size_t)(i00 + qrow[r]) * HIDD + col] = v0;
            float v1 = acc1[t][r] / den1;
            v1 = v1 > 0.f ? v1 : expm1f(v1);
            res[(size_t)(i01 + qrow[r]) * HIDD + col] = v1;
        }
    }
}

// ---------------- GAT layer 1 fallback (register P, VF layout) ----------------
__global__ __launch_bounds__(256) void k_gat1(const u64_t* __restrict__ mask,
        const float* __restrict__ e1, const float* __restrict__ e2,
        const uint_t* __restrict__ e2mE,
        const ushort_t* __restrict__ VF, float* __restrict__ res){
    __shared__ __align__(16) float e2s[NNODE];
    __shared__ u64_t msk[16][NMSK + 1];
    int bid = blockIdx.x;
    int b8 = bid & 7, a = bid >> 3;
    int ch = b8 >> 2;
    int rg = a * 4 + (b8 & 3);
    int i0 = rg * 16;
    int tid = threadIdx.x;
    int w = tid >> 6, l = tid & 63, lm = l & 15, lh = l >> 4;
    int cbase = ch * 256 + w * 64;
    int qrow[4], vcol[4];
    calib_cd(lm, qrow, vcol);
    for (int k = tid; k < NNODE; k += 256) e2s[k] = e2[k];
    for (int k = tid; k < 16 * NMSK; k += 256) msk[k / NMSK][k % NMSK] = mask[(size_t)i0 * NMSK + k];
    __syncthreads();
    float e1i = e1[i0 + lm];
    float M = lrelu(e1i + decf(*e2mE));
    float lsum = 0.f;
    f32x4 acc[4] = {};
    const ushort_t* Vp[4];
    #pragma unroll
    for (int t = 0; t < 4; t++)
        Vp[t] = VF + (size_t)((cbase >> 4) + t) * NKT * 512 + l * 8;
    bf16x8 vc[4][2], vn[4][2];
    #pragma unroll
    for (int t = 0; t < 4; t++)
        #pragma unroll
        for (int h = 0; h < 2; h++) vc[t][h] = *(const bf16x8*)(Vp[t] + h * 512);
    for (int j0 = 0; j0 < NNODE; j0 += 64){
        u64_t word = msk[lm][j0 >> 6];
        int jn = j0 + 64;
        if (jn < NNODE){
            size_t nb = (size_t)(jn >> 5) * 512;
            #pragma unroll
            for (int t = 0; t < 4; t++)
                #pragma unroll
                for (int h = 0; h < 2; h++) vn[t][h] = *(const bf16x8*)(Vp[t] + nb + h * 512);
        }
        #pragma unroll
        for (int h = 0; h < 2; h++){
            int jb = j0 + h*32 + lh*8;
            float4 fA = *(const float4*)&e2s[jb];
            float4 fB = *(const float4*)&e2s[jb + 4];
            float ea[8] = {fA.x, fA.y, fA.z, fA.w, fB.x, fB.y, fB.z, fB.w};
            int sh = h*32 + lh*8;
            bf16x8 pk;
            float ls = 0.f;
            #pragma unroll
            for (int e = 0; e < 8; e++){
                float p = ((word >> (sh + e)) & 1ull) ? __expf(lrelu(e1i + ea[e]) - M) : 0.f;
                ushort_t pb = f2b(p);
                ((ushort_t*)&pk)[e] = pb;
                ls += b2f(pb);
            }
            lsum += ls;
            #pragma unroll
            for (int t = 0; t < 4; t++)
                acc[t] = __builtin_amdgcn_mfma_f32_16x16x32_bf16(pk, vc[t][h], acc[t], 0, 0, 0);
        }
        #pragma unroll
        for (int t = 0; t < 4; t++)
            #pragma unroll
            for (int h = 0; h < 2; h++) vc[t][h] = vn[t][h];
    }
    lsum += __shfl_xor(lsum, 16);
    lsum += __shfl_xor(lsum, 32);
    #pragma unroll
    for (int t = 0; t < 4; t++){
        #pragma unroll
        for (int r = 0; r < 4; r++){
            float den = __shfl(lsum, qrow[r]);
            int row = qrow[r];
            int col = cbase + t*16 + vcol[r];
            float v = acc[t][r] / den;
            v = v > 0.f ? v : expm1f(v);
            res[(size_t)(i0 + row) * HIDD + col] = v;
        }
    }
}

// ---------------- GAT layer 2: 8-wave j-split, fragment-native V2 ----------------
#define JSPAN (NNODE/8)
__global__ __launch_bounds__(512) void k_gat2(const u64_t* __restrict__ mask,
        const float* __restrict__ o1, const float* __restrict__ o2,
        const float* __restrict__ t1, const float* __restrict__ t2,
        const uint_t* __restrict__ o2mE, const uint_t* __restrict__ t2mE,
        const ushort_t* __restrict__ VF2, float* __restrict__ out2){
    __shared__ float accs[8][16][64];
    __shared__ float lsums[8][16];
    __shared__ u64_t msk[16][NMSK + 1];
    int i0 = blockIdx.x * 16;
    int tid = threadIdx.x;
    int w = tid >> 6, l = tid & 63, lm = l & 15, lh = l >> 4;
    for (int k = tid; k < 16 * NMSK; k += 512) msk[k / NMSK][k % NMSK] = mask[(size_t)i0 * NMSK + k];
    __syncthreads();
    int qrow[4], vcol[4];
    calib_cd(lm, qrow, vcol);
    int jbase = w * JSPAN;
    float o1v = o1[i0 + lm], t1v = t1[i0 + lm];
    float M = lrelu(o1v + decf(*o2mE)) + lrelu(t1v + decf(*t2mE));
    float lsum = 0.f;
    f32x4 acc[4] = {};
    const float* o2p = o2 + jbase + lh * 8;
    const float* t2p = t2 + jbase + lh * 8;
    float4 oA = *(const float4*)(o2p), oB = *(const float4*)(o2p + 4);
    float4 tA = *(const float4*)(t2p), tB = *(const float4*)(t2p + 4);
    const ushort_t* Vp[4];
    #pragma unroll
    for (int t = 0; t < 4; t++)
        Vp[t] = VF2 + (size_t)t * NKT * 512 + (size_t)(jbase >> 5) * 512 + l * 8;
    bf16x8 vcur[4], vnxt[4];
    #pragma unroll
    for (int t = 0; t < 4; t++) vcur[t] = *(const bf16x8*)(Vp[t]);

    for (int js = 0; js < JSPAN; js += 32){
        u64_t w64 = msk[lm][(jbase + js) >> 6];
        int sh = (js + lh * 8) & 63;
        float oa[8] = {oA.x, oA.y, oA.z, oA.w, oB.x, oB.y, oB.z, oB.w};
        float ta[8] = {tA.x, tA.y, tA.z, tA.w, tB.x, tB.y, tB.z, tB.w};
        bf16x8 pk;
        float ls = 0.f;
        #pragma unroll
        for (int e = 0; e < 8; e++){
            float p = ((w64 >> (sh + e)) & 1ull) ?
                      __expf(lrelu(o1v + oa[e]) + lrelu(t1v + ta[e]) - M) : 0.f;
            ushort_t pb = f2b(p);
            ((ushort_t*)&pk)[e] = pb;
            ls += b2f(pb);
        }
        lsum += ls;
        int jn = js + 32;
        if (jn < JSPAN){
            oA = *(const float4*)(o2p + jn); oB = *(const float4*)(o2p + jn + 4);
            tA = *(const float4*)(t2p + jn); tB = *(const float4*)(t2p + jn + 4);
            #pragma unroll
            for (int t = 0; t < 4; t++)
                vnxt[t] = *(const bf16x8*)(Vp[t] + (size_t)(jn >> 5) * 512);
        }
        #pragma unroll
        for (int t = 0; t < 4; t++)
            acc[t] = __builtin_amdgcn_mfma_f32_16x16x32_bf16(pk, vcur[t], acc[t], 0, 0, 0);
        #pragma unroll
        for (int t = 0; t < 4; t++) vcur[t] = vnxt[t];
    }
    lsum += __shfl_xor(lsum, 16);
    lsum += __shfl_xor(lsum, 32);
    if (lh == 0) lsums[w][lm] = lsum;
    #pragma unroll
    for (int t = 0; t < 4; t++)
        #pragma unroll
        for (int r = 0; r < 4; r++)
            accs[w][qrow[r]][t*16 + vcol[r]] = acc[t][r];
    __syncthreads();
    #pragma unroll
    for (int rr = 0; rr < 2; rr++){
        int row = w * 2 + rr;
        float den = 0.f, v = 0.f;
        #pragma unroll
        for (int q = 0; q < 8; q++){ den += lsums[q][row]; v += accs[q][row][l]; }
        out2[(size_t)(i0 + row) * NCLSD + l] = v / den;
    }
}

// ---------------- row-wise log_softmax over 64 classes ----------------
__global__ void k_logsoftmax(const float* __restrict__ out2, float* __restrict__ out){
    int w = threadIdx.x >> 6, l = threadIdx.x & 63;
    int row = blockIdx.x * 4 + w;
    float v = out2[(size_t)row * NCLSD + l];
    float mx = v;
    #pragma unroll
    for (int o = 32; o; o >>= 1) mx = fmaxf(mx, __shfl_xor(mx, o));
    float ex = __expf(v - mx);
    #pragma unroll
    for (int o = 32; o; o >>= 1) ex += __shfl_xor(ex, o);
    out[(size_t)row * NCLSD + l] = v - mx - logf(ex);
}

// ---------------- launch ----------------
extern "C" void kernel_launch(void* const* d_in, const int* in_sizes, int n_in,
                              void* d_out, int out_size, void* d_ws, size_t ws_size,
                              hipStream_t stream){
    const float* X   = (const float*)d_in[0];
    const int*   adj = (const int*)d_in[1];
    const float* Wg  = (const float*)d_in[2];
    const float* ag  = (const float*)d_in[3];
    const float* Wt  = (const float*)d_in[4];
    const float* at  = (const float*)d_in[5];
    const float* Wo  = (const float*)d_in[6];
    const float* ao  = (const float*)d_in[7];
    float* out = (float*)d_out;

    char* ws = (char*)d_ws;
    size_t off = 0;
    auto take = [&](size_t n){ char* p = ws + off; off = (off + n + 255) & ~(size_t)255; return p; };
    u64_t*    maskb = (u64_t*)take((size_t)NNODE * NMSK * 8);
    ushort_t* VF    = (ushort_t*)take((size_t)HIDD * NNODE * 2);   // fragment layout Wh1
    float*    res   = (float*)take((size_t)NNODE * HIDD * 4);
    float*    out2b = (float*)take((size_t)NNODE * NCLSD * 4);
    ushort_t* VF2   = (ushort_t*)take((size_t)NCLSD * NNODE * 2);  // fragment layout Wh2
    ushort_t* XF    = (ushort_t*)take((size_t)NNODE * FEATD * 2);  // fragment layout X
    ushort_t* WgF   = (ushort_t*)take((size_t)FEATD * HIDD * 2);   // fragment layout Wg
    ushort_t* WoT   = (ushort_t*)take((size_t)HIDD * NCLSD * 2);
    float* e1v  = (float*)take(NNODE * 4);
    float* e2v  = (float*)take(NNODE * 4);
    float* t1v  = (float*)take(NNODE * 4);
    float* t2v  = (float*)take(NNODE * 4);
    float* o1v  = (float*)take(NNODE * 4);
    float* o2v  = (float*)take(NNODE * 4);
    float* wg1  = (float*)take(FEATD * 4);
    float* wg2  = (float*)take(FEATD * 4);
    float* wt1  = (float*)take(HIDD * 4);
    float* wt2  = (float*)take(HIDD * 4);
    uint_t* scal = (uint_t*)take(256);
    uint_t* e2mE = scal, * t2mE = scal + 1, * o2mE = scal + 2;

    // P fragment buffer (allocated last; only used if ws is big enough)
    size_t pbytes = (size_t)NNODE * NNODE * 2;
    bool bigws = (off + pbytes + NNODE * 4 + 4096) <= ws_size;
    ushort_t* Pbuf  = bigws ? (ushort_t*)take(pbytes) : nullptr;
    float*    lsumv = bigws ? (float*)take(NNODE * 4) : nullptr;

    // reset encoded-max slots (0 == -inf in the monotone encoding)
    hipMemsetAsync(scal, 0, 256, stream);
    // adj -> bitmask (reads adj once)
    k_adjmask<<<dim3(2048), dim3(256), 0, stream>>>(adj, maskb);
    // weight prep
    k_transpose_bf16<<<dim3((HIDD*NCLSD + 255)/256), dim3(256), 0, stream>>>(Wo, WoT, HIDD, NCLSD);
    k_fold<<<dim3(FEATD/4), dim3(256), 0, stream>>>(Wg, ag, wg1, wg2, HIDD);
    k_fold<<<dim3(HIDD/4),  dim3(256), 0, stream>>>(Wt, at, wt1, wt2, HIDD);
    k_wgfrag<<<dim3(((HIDD/16)*NKTX*64 + 255)/256), dim3(256), 0, stream>>>(Wg, WgF);
    // fused X fragmentize + layer-1 scores + e2max
    k_xprep<<<dim3(NNODE/16), dim3(256), 0, stream>>>(X, wg1, wg2, XF, e1v, e2v, e2mE);
    // Wh1 via MFMA
    k_gemm_xw<<<dim3(NNODE/16), dim3(512), 0, stream>>>(XF, WgF, VF);
    // GAT layer 1
    if (bigws){
        k_pgen<<<dim3(NNODE/16), dim3(256), 0, stream>>>(maskb, e1v, e2v, e2mE, Pbuf, lsumv);
        k_gat1g<<<dim3(NNODE/64 * 8), dim3(128), 0, stream>>>(Pbuf, lsumv, VF, res);
    } else {
        k_gat1<<<dim3(NNODE/16 * 2), dim3(256), 0, stream>>>(maskb, e1v, e2v, e2mE, VF, res);
    }
    // tree scores via fold + t2max
    k_rowvec2_max<<<dim3(NNODE/4), dim3(256), 0, stream>>>(res, wt1, wt2, t1v, t2v, t2mE, HIDD);
    // layer-2 prep (MFMA; emits VF2 + o1/o2/o2max fused)
    k_gemm_out<<<dim3(NNODE/64), dim3(256), 0, stream>>>(res, WoT, ao, VF2, o1v, o2v, o2mE);
    // GAT layer 2 + log_softmax
    k_gat2<<<dim3(NNODE/16), dim3(512), 0, stream>>>(maskb, o1v, o2v, t1v, t2v, o2mE, t2mE, VF2, out2b);
    k_logsoftmax<<<dim3(NNODE/4), dim3(256), 0, stream>>>(out2b, out);
}

// Round 17
// 290.852 us; speedup vs baseline: 1.4042x; 1.4042x over previous
//
#include <hip/hip_runtime.h>

#define NNODE 6144
#define FEATD 512
#define HIDD  512
#define NCLSD 64
#define NMSK  (NNODE/64)   // 96 mask words per row
#define NKT   (NNODE/32)   // 192 k-tiles (node dim)
#define NKTX  (FEATD/32)   // 16 k-tiles (feature dim)
#define LALPHA 0.2f

typedef unsigned short ushort_t;
typedef unsigned char u8_t;
typedef unsigned long long u64_t;
typedef short bf16x8 __attribute__((ext_vector_type(8)));
typedef float f32x4 __attribute__((ext_vector_type(4)));

__device__ __forceinline__ float lrelu(float x){ return x > 0.f ? x : LALPHA * x; }

__device__ __forceinline__ ushort_t f2b(float x){
    union { float f; unsigned u; } v; v.f = x;
    unsigned r = v.u + 0x7fffu + ((v.u >> 16) & 1u);
    return (ushort_t)(r >> 16);
}
__device__ __forceinline__ float b2f(ushort_t u){
    union { unsigned u; float f; } v; v.u = ((unsigned)u) << 16; return v.f;
}

// Runtime C/D-layout calibration (round-8 validated)
__device__ __forceinline__ void calib_cd(int lm, int* qrow, int* vcol){
    bf16x8 ai, as;
    ushort_t vi = f2b((float)(lm + 1));
    ushort_t vs = f2b(0.03125f);
    #pragma unroll
    for (int e = 0; e < 8; e++){ ((ushort_t*)&ai)[e] = vi; ((ushort_t*)&as)[e] = vs; }
    f32x4 z = {0.f, 0.f, 0.f, 0.f};
    f32x4 d1 = __builtin_amdgcn_mfma_f32_16x16x32_bf16(ai, as, z, 0, 0, 0);
    f32x4 d2 = __builtin_amdgcn_mfma_f32_16x16x32_bf16(as, ai, z, 0, 0, 0);
    #pragma unroll
    for (int r = 0; r < 4; r++){
        qrow[r] = (int)(d1[r] + 0.5f) - 1;
        vcol[r] = (int)(d2[r] + 0.5f) - 1;
    }
}

// ---------------- adj (int32) -> bitmask (fallback path only) ----------------
__global__ void k_adjmask(const int* __restrict__ adj, u64_t* __restrict__ mask){
    int lane = threadIdx.x & 63;
    size_t wid = ((size_t)blockIdx.x * blockDim.x + threadIdx.x) >> 6;
    size_t nw = (size_t)NNODE * NNODE / 64;
    size_t stride = ((size_t)gridDim.x * blockDim.x) >> 6;
    for (size_t q = wid; q < nw; q += stride){
        int a = adj[q * 64 + lane];
        u64_t b = __ballot(a > 0);
        if (lane == 0) mask[q] = b;
    }
}

// out1[r]=W[r]·a[0:K]; out2[r]=W[r]·a[K:2K]  (one wave per row)
__global__ void k_fold(const float* __restrict__ W, const float* __restrict__ a,
                       float* __restrict__ out1, float* __restrict__ out2, int K){
    int row  = (blockIdx.x * blockDim.x + threadIdx.x) >> 6;
    int lane = threadIdx.x & 63;
    const float* wr = W + (size_t)row * K;
    float s1 = 0.f, s2 = 0.f;
    for (int c = lane; c < K; c += 64){ float w = wr[c]; s1 += w * a[c]; s2 += w * a[K + c]; }
    #pragma unroll
    for (int m = 32; m; m >>= 1){ s1 += __shfl_xor(s1, m); s2 += __shfl_xor(s2, m); }
    if (lane == 0){ out1[row] = s1; out2[row] = s2; }
}

// ---------------- o1/o2 = A @ {v1,v2}  (one wave per row) ----------------
__global__ void k_rowvec2_f32(const float* __restrict__ A, const float* __restrict__ v1,
                              const float* __restrict__ v2, float* __restrict__ o1,
                              float* __restrict__ o2, int K){
    int row  = (blockIdx.x * blockDim.x + threadIdx.x) >> 6;
    int lane = threadIdx.x & 63;
    const float* r = A + (size_t)row * K;
    float s1 = 0.f, s2 = 0.f;
    for (int c = lane; c < K; c += 64){ float x = r[c]; s1 += x * v1[c]; s2 += x * v2[c]; }
    #pragma unroll
    for (int m = 32; m; m >>= 1){ s1 += __shfl_xor(s1, m); s2 += __shfl_xor(s2, m); }
    if (lane == 0){ o1[row] = s1; o2[row] = s2; }
}

// ---------------- *out = max(x[0..n)) ----------------
__global__ void k_max(const float* __restrict__ x, int n, float* __restrict__ out){
    __shared__ float sm[16];
    float m = -3.0e38f;
    for (int i = threadIdx.x; i < n; i += blockDim.x) m = fmaxf(m, x[i]);
    #pragma unroll
    for (int s = 32; s; s >>= 1) m = fmaxf(m, __shfl_xor(m, s));
    if ((threadIdx.x & 63) == 0) sm[threadIdx.x >> 6] = m;
    __syncthreads();
    if (threadIdx.x == 0){
        float mm = sm[0];
        for (int i = 1; i < (int)(blockDim.x >> 6); i++) mm = fmaxf(mm, sm[i]);
        *out = mm;
    }
}

// ---------------- X -> XF bf16 fragment layout ----------------
__global__ __launch_bounds__(256) void k_xfrag(const float* __restrict__ X,
                                               ushort_t* __restrict__ XF){
    int ri = blockIdx.x;
    int tid = threadIdx.x;
    int r = tid >> 4, q = tid & 15;
    const float* xp = X + (size_t)(ri * 16 + r) * FEATD;
    ushort_t* xb = XF + (size_t)ri * NKTX * 512;
    for (int j0 = 0; j0 < FEATD; j0 += 128){
        int j = j0 + q * 8;
        float4 fA = *(const float4*)(xp + j);
        float4 fB = *(const float4*)(xp + j + 4);
        float xa[8] = {fA.x, fA.y, fA.z, fA.w, fB.x, fB.y, fB.z, fB.w};
        bf16x8 pk;
        #pragma unroll
        for (int e = 0; e < 8; e++) ((ushort_t*)&pk)[e] = f2b(xa[e]);
        int ki = j >> 5;
        int lh = (j >> 3) & 3;
        *(bf16x8*)(xb + ((size_t)ki * 512 + (size_t)(r + (lh << 4)) * 8)) = pk;
    }
}

// ---------------- Wg -> WgF fragment layout (B-operand) ----------------
__global__ __launch_bounds__(256) void k_wgfrag(const float* __restrict__ Wg,
                                                ushort_t* __restrict__ WgF){
    int gid = blockIdx.x * 256 + threadIdx.x;
    if (gid >= (HIDD/16) * NKTX * 64) return;
    int l = gid & 63, unit = gid >> 6;
    int ci = unit / NKTX, ki = unit - ci * NKTX;
    int lm = l & 15, lh = l >> 4;
    bf16x8 pk;
    #pragma unroll
    for (int e = 0; e < 8; e++)
        ((ushort_t*)&pk)[e] = f2b(Wg[(size_t)(ki*32 + lh*8 + e) * HIDD + ci*16 + lm]);
    *(bf16x8*)(WgF + (size_t)unit * 512 + (size_t)l * 8) = pk;
}

// ---------------- Wo -> WoF fragment layout (B-operand for gemm_out) ----------------
// WoF[(ci*NKTX + ki)*512 + l*8 + e] = bf16(Wo[ki*32 + (l>>4)*8 + e][ci*16 + (l&15)])
__global__ __launch_bounds__(256) void k_wofrag(const float* __restrict__ Wo,
                                                ushort_t* __restrict__ WoF){
    int gid = blockIdx.x * 256 + threadIdx.x;
    if (gid >= (NCLSD/16) * NKTX * 64) return;
    int l = gid & 63, unit = gid >> 6;
    int ci = unit / NKTX, ki = unit - ci * NKTX;
    int lm = l & 15, lh = l >> 4;
    bf16x8 pk;
    #pragma unroll
    for (int e = 0; e < 8; e++)
        ((ushort_t*)&pk)[e] = f2b(Wo[(size_t)(ki*32 + lh*8 + e) * NCLSD + ci*16 + lm]);
    *(bf16x8*)(WoF + (size_t)unit * 512 + (size_t)l * 8) = pk;
}

// ---------------- Wh1 = X @ Wg via MFMA -> VF fragments ----------------
__global__ __launch_bounds__(512) void k_gemm_xw(const ushort_t* __restrict__ XF,
        const ushort_t* __restrict__ WgF, ushort_t* __restrict__ VF){
    int ri = blockIdx.x;
    int i0 = ri * 16;
    int w = threadIdx.x >> 6, l = threadIdx.x & 63, lm = l & 15;
    int c0 = w * 64;
    int qrow[4], vcol[4];
    calib_cd(lm, qrow, vcol);
    f32x4 acc[4] = {};
    const ushort_t* Ap = XF + (size_t)ri * NKTX * 512 + l * 8;
    const ushort_t* Bp[4];
    #pragma unroll
    for (int t = 0; t < 4; t++)
        Bp[t] = WgF + (size_t)((c0 >> 4) + t) * NKTX * 512 + l * 8;
    for (int ki = 0; ki < NKTX; ki++){
        bf16x8 af = *(const bf16x8*)(Ap + (size_t)ki * 512);
        #pragma unroll
        for (int t = 0; t < 4; t++){
            bf16x8 bf = *(const bf16x8*)(Bp[t] + (size_t)ki * 512);
            acc[t] = __builtin_amdgcn_mfma_f32_16x16x32_bf16(af, bf, acc[t], 0, 0, 0);
        }
    }
    #pragma unroll
    for (int t = 0; t < 4; t++){
        int ci = (c0 >> 4) + t;
        #pragma unroll
        for (int r = 0; r < 4; r++){
            int node = i0 + qrow[r];
            size_t vo = ((size_t)ci * NKT + (node >> 5)) * 512
                      + (size_t)(vcol[r] + ((node >> 3) & 3) * 16) * 8 + (node & 7);
            VF[vo] = f2b(acc[t][r]);
        }
    }
}

// ---------------- Wh2 = res @ Wo via MFMA; emits fp32 Wh2 + fragment VF2 ----------------
__global__ __launch_bounds__(256) void k_gemm_out(const float* __restrict__ res,
        const ushort_t* __restrict__ WoF, float* __restrict__ Wh2, ushort_t* __restrict__ VF2){
    int w = threadIdx.x >> 6, l = threadIdx.x & 63, lm = l & 15, lh = l >> 4;
    int i0 = blockIdx.x * 64 + w * 16;
    int qrow[4], vcol[4];
    calib_cd(lm, qrow, vcol);
    f32x4 acc[4] = {};
    const float* ap = res + (size_t)(i0 + lm) * HIDD + lh * 8;
    for (int k0 = 0; k0 < HIDD; k0 += 32){
        int ki = k0 >> 5;
        float4 x0 = *(const float4*)(ap + k0);
        float4 x1 = *(const float4*)(ap + k0 + 4);
        float xa[8] = {x0.x, x0.y, x0.z, x0.w, x1.x, x1.y, x1.z, x1.w};
        bf16x8 af;
        #pragma unroll
        for (int e = 0; e < 8; e++) ((ushort_t*)&af)[e] = f2b(xa[e]);
        #pragma unroll
        for (int t = 0; t < 4; t++){
            bf16x8 bf = *(const bf16x8*)(WoF + (size_t)(t * NKTX + ki) * 512 + l * 8);
            acc[t] = __builtin_amdgcn_mfma_f32_16x16x32_bf16(af, bf, acc[t], 0, 0, 0);
        }
    }
    #pragma unroll
    for (int t = 0; t < 4; t++){
        #pragma unroll
        for (int r = 0; r < 4; r++){
            int node = i0 + qrow[r], col = t*16 + vcol[r];
            float v = acc[t][r];
            Wh2[(size_t)node * NCLSD + col] = v;
            size_t vo = ((size_t)t * NKT + (node >> 5)) * 512
                      + (size_t)(vcol[r] + ((node >> 3) & 3) * 16) * 8 + (node & 7);
            VF2[vo] = f2b(v);
        }
    }
}

// ---------------- P-gen v2: reads adj directly, emits PF + byte mask + row sums ----------------
__global__ __launch_bounds__(256) void k_pgen(const int* __restrict__ adj,
        const float* __restrict__ e1, const float* __restrict__ e2,
        const float* __restrict__ e2max, ushort_t* __restrict__ PF,
        float* __restrict__ lsum, u8_t* __restrict__ mask8){
    __shared__ float e2s[NNODE];
    int ri = blockIdx.x;
    int i0 = ri * 16;
    int tid = threadIdx.x;
    int r = tid >> 4, q = tid & 15;
    for (int k = tid; k < NNODE; k += 256) e2s[k] = e2[k];
    __syncthreads();
    float e1i = e1[i0 + r];
    float M = lrelu(e1i + *e2max);   // exact upper bound (softmax shift-invariant)
    float rsum = 0.f;
    ushort_t* pfb = PF + (size_t)ri * NKT * 512;
    const int* adjp = adj + (size_t)(i0 + r) * NNODE;
    u8_t* mrow = mask8 + (size_t)(i0 + r) * (NMSK * 8);
    for (int j0 = 0; j0 < NNODE; j0 += 128){
        int j = j0 + q * 8;
        int4 a0 = *(const int4*)(adjp + j);
        int4 a1 = *(const int4*)(adjp + j + 4);
        int av[8] = {a0.x, a0.y, a0.z, a0.w, a1.x, a1.y, a1.z, a1.w};
        float4 fA = *(const float4*)&e2s[j];
        float4 fB = *(const float4*)&e2s[j + 4];
        float ea[8] = {fA.x, fA.y, fA.z, fA.w, fB.x, fB.y, fB.z, fB.w};
        bf16x8 pk;
        unsigned byte = 0;
        #pragma unroll
        for (int e = 0; e < 8; e++){
            int bit = av[e] > 0;
            byte |= (unsigned)bit << e;
            float p = bit ? __expf(lrelu(e1i + ea[e]) - M) : 0.f;
            ushort_t pb = f2b(p);
            ((ushort_t*)&pk)[e] = pb;
            rsum += b2f(pb);
        }
        mrow[j >> 3] = (u8_t)byte;
        int ki = j >> 5;
        int lh = (j >> 3) & 3;
        *(bf16x8*)(pfb + ((size_t)ki * 512 + (size_t)(r + (lh << 4)) * 8)) = pk;
    }
    #pragma unroll
    for (int o = 8; o; o >>= 1) rsum += __shfl_xor(rsum, o);
    if (q == 0) lsum[i0 + r] = rsum;
}

// ---------------- GAT1 GEMM (round-15 proven): 64-row x 64-col blocks, stacked waves ----------------
__global__ __launch_bounds__(256) void k_gat1g(const ushort_t* __restrict__ PF,
        const float* __restrict__ lsum, const ushort_t* __restrict__ VF,
        float* __restrict__ res){
    int bid = blockIdx.x;
    int c8 = bid & 7, rg = bid >> 3;
    int tid = threadIdx.x;
    int w = tid >> 6, l = tid & 63, lm = l & 15;
    int ri = rg * 4 + w;
    int i0 = ri * 16;
    int cbase = c8 * 64;
    int qrow[4], vcol[4];
    calib_cd(lm, qrow, vcol);
    f32x4 acc[4] = {};
    const ushort_t* Ap = PF + (size_t)ri * NKT * 512 + l * 8;
    const ushort_t* Vp[4];
    #pragma unroll
    for (int t = 0; t < 4; t++)
        Vp[t] = VF + (size_t)(c8 * 4 + t) * NKT * 512 + l * 8;
    bf16x8 a0c = *(const bf16x8*)(Ap);
    bf16x8 a1c = *(const bf16x8*)(Ap + 512);
    bf16x8 vc[4][2], vn[4][2], a0n = {}, a1n = {};
    #pragma unroll
    for (int t = 0; t < 4; t++){
        vc[t][0] = *(const bf16x8*)(Vp[t]);
        vc[t][1] = *(const bf16x8*)(Vp[t] + 512);
    }
    for (int s = 0; s < NKT/2; s++){
        size_t nb = (size_t)(s + 1) * 1024;
        if (s + 1 < NKT/2){
            a0n = *(const bf16x8*)(Ap + nb);
            a1n = *(const bf16x8*)(Ap + nb + 512);
            #pragma unroll
            for (int t = 0; t < 4; t++){
                vn[t][0] = *(const bf16x8*)(Vp[t] + nb);
                vn[t][1] = *(const bf16x8*)(Vp[t] + nb + 512);
            }
        }
        #pragma unroll
        for (int t = 0; t < 4; t++){
            acc[t] = __builtin_amdgcn_mfma_f32_16x16x32_bf16(a0c, vc[t][0], acc[t], 0, 0, 0);
            acc[t] = __builtin_amdgcn_mfma_f32_16x16x32_bf16(a1c, vc[t][1], acc[t], 0, 0, 0);
        }
        a0c = a0n; a1c = a1n;
        #pragma unroll
        for (int t = 0; t < 4; t++){ vc[t][0] = vn[t][0]; vc[t][1] = vn[t][1]; }
    }
    float den[4];
    #pragma unroll
    for (int r = 0; r < 4; r++) den[r] = lsum[i0 + qrow[r]];
    #pragma unroll
    for (int t = 0; t < 4; t++){
        #pragma unroll
        for (int r = 0; r < 4; r++){
            int row = qrow[r];
            int col = cbase + t*16 + vcol[r];
            float v = acc[t][r] / den[r];
            v = v > 0.f ? v : expm1f(v);   // elu
            res[(size_t)(i0 + row) * HIDD + col] = v;
        }
    }
}

// ---------------- GAT layer 1 fallback (register P, VF layout) ----------------
__global__ __launch_bounds__(256) void k_gat1(const u64_t* __restrict__ mask,
        const float* __restrict__ e1, const float* __restrict__ e2,
        const float* __restrict__ e2max,
        const ushort_t* __restrict__ VF, float* __restrict__ res){
    __shared__ __align__(16) float e2s[NNODE];
    __shared__ u64_t msk[16][NMSK + 1];
    int bid = blockIdx.x;
    int b8 = bid & 7, a = bid >> 3;
    int ch = b8 >> 2;
    int rg = a * 4 + (b8 & 3);
    int i0 = rg * 16;
    int tid = threadIdx.x;
    int w = tid >> 6, l = tid & 63, lm = l & 15, lh = l >> 4;
    int cbase = ch * 256 + w * 64;
    int qrow[4], vcol[4];
    calib_cd(lm, qrow, vcol);
    for (int k = tid; k < NNODE; k += 256) e2s[k] = e2[k];
    for (int k = tid; k < 16 * NMSK; k += 256) msk[k / NMSK][k % NMSK] = mask[(size_t)i0 * NMSK + k];
    __syncthreads();
    float e1i = e1[i0 + lm];
    float M = lrelu(e1i + *e2max);
    float lsum = 0.f;
    f32x4 acc[4] = {};
    const ushort_t* Vp[4];
    #pragma unroll
    for (int t = 0; t < 4; t++)
        Vp[t] = VF + (size_t)((cbase >> 4) + t) * NKT * 512 + l * 8;
    bf16x8 vc[4][2], vn[4][2];
    #pragma unroll
    for (int t = 0; t < 4; t++)
        #pragma unroll
        for (int h = 0; h < 2; h++) vc[t][h] = *(const bf16x8*)(Vp[t] + h * 512);
    for (int j0 = 0; j0 < NNODE; j0 += 64){
        u64_t word = msk[lm][j0 >> 6];
        int jn = j0 + 64;
        if (jn < NNODE){
            size_t nb = (size_t)(jn >> 5) * 512;
            #pragma unroll
            for (int t = 0; t < 4; t++)
                #pragma unroll
                for (int h = 0; h < 2; h++) vn[t][h] = *(const bf16x8*)(Vp[t] + nb + h * 512);
        }
        #pragma unroll
        for (int h = 0; h < 2; h++){
            int jb = j0 + h*32 + lh*8;
            float4 fA = *(const float4*)&e2s[jb];
            float4 fB = *(const float4*)&e2s[jb + 4];
            float ea[8] = {fA.x, fA.y, fA.z, fA.w, fB.x, fB.y, fB.z, fB.w};
            int sh = h*32 + lh*8;
            bf16x8 pk;
            float ls = 0.f;
            #pragma unroll
            for (int e = 0; e < 8; e++){
                float p = ((word >> (sh + e)) & 1ull) ? __expf(lrelu(e1i + ea[e]) - M) : 0.f;
                ushort_t pb = f2b(p);
                ((ushort_t*)&pk)[e] = pb;
                ls += b2f(pb);
            }
            lsum += ls;
            #pragma unroll
            for (int t = 0; t < 4; t++)
                acc[t] = __builtin_amdgcn_mfma_f32_16x16x32_bf16(pk, vc[t][h], acc[t], 0, 0, 0);
        }
        #pragma unroll
        for (int t = 0; t < 4; t++)
            #pragma unroll
            for (int h = 0; h < 2; h++) vc[t][h] = vn[t][h];
    }
    lsum += __shfl_xor(lsum, 16);
    lsum += __shfl_xor(lsum, 32);
    #pragma unroll
    for (int t = 0; t < 4; t++){
        #pragma unroll
        for (int r = 0; r < 4; r++){
            float den = __shfl(lsum, qrow[r]);
            int row = qrow[r];
            int col = cbase + t*16 + vcol[r];
            float v = acc[t][r] / den;
            v = v > 0.f ? v : expm1f(v);
            res[(size_t)(i0 + row) * HIDD + col] = v;
        }
    }
}

// ---------------- GAT layer 2: 8-wave j-split, fragment V2, byte-mask ----------------
#define JSPAN (NNODE/8)
__global__ __launch_bounds__(512) void k_gat2(const u64_t* __restrict__ mask,
        const float* __restrict__ o1, const float* __restrict__ o2,
        const float* __restrict__ t1, const float* __restrict__ t2,
        const float* __restrict__ o2max, const float* __restrict__ t2max,
        const ushort_t* __restrict__ VF2, float* __restrict__ out2){
    __shared__ float accs[8][16][64];
    __shared__ float lsums[8][16];
    __shared__ u64_t msk[16][NMSK + 1];
    int i0 = blockIdx.x * 16;
    int tid = threadIdx.x;
    int w = tid >> 6, l = tid & 63, lm = l & 15, lh = l >> 4;
    for (int k = tid; k < 16 * NMSK; k += 512) msk[k / NMSK][k % NMSK] = mask[(size_t)i0 * NMSK + k];
    __syncthreads();
    int qrow[4], vcol[4];
    calib_cd(lm, qrow, vcol);
    int jbase = w * JSPAN;
    float o1v = o1[i0 + lm], t1v = t1[i0 + lm];
    float M = lrelu(o1v + *o2max) + lrelu(t1v + *t2max);
    float lsum = 0.f;
    f32x4 acc[4] = {};
    const float* o2p = o2 + jbase + lh * 8;
    const float* t2p = t2 + jbase + lh * 8;
    float4 oA = *(const float4*)(o2p), oB = *(const float4*)(o2p + 4);
    float4 tA = *(const float4*)(t2p), tB = *(const float4*)(t2p + 4);
    const u8_t* mrow = (const u8_t*)&msk[lm][0];
    const ushort_t* Vp[4];
    #pragma unroll
    for (int t = 0; t < 4; t++)
        Vp[t] = VF2 + (size_t)t * NKT * 512 + (size_t)(jbase >> 5) * 512 + l * 8;
    bf16x8 vcur[4], vnxt[4];
    #pragma unroll
    for (int t = 0; t < 4; t++) vcur[t] = *(const bf16x8*)(Vp[t]);

    for (int js = 0; js < JSPAN; js += 32){
        unsigned b8v = mrow[(jbase + js + lh * 8) >> 3];
        float oa[8] = {oA.x, oA.y, oA.z, oA.w, oB.x, oB.y, oB.z, oB.w};
        float ta[8] = {tA.x, tA.y, tA.z, tA.w, tB.x, tB.y, tB.z, tB.w};
        bf16x8 pk;
        float ls = 0.f;
        #pragma unroll
        for (int e = 0; e < 8; e++){
            float p = ((b8v >> e) & 1u) ?
                      __expf(lrelu(o1v + oa[e]) + lrelu(t1v + ta[e]) - M) : 0.f;
            ushort_t pb = f2b(p);
            ((ushort_t*)&pk)[e] = pb;
            ls += b2f(pb);
        }
        lsum += ls;
        int jn = js + 32;
        if (jn < JSPAN){
            oA = *(const float4*)(o2p + jn); oB = *(const float4*)(o2p + jn + 4);
            tA = *(const float4*)(t2p + jn); tB = *(const float4*)(t2p + jn + 4);
            #pragma unroll
            for (int t = 0; t < 4; t++)
                vnxt[t] = *(const bf16x8*)(Vp[t] + (size_t)(jn >> 5) * 512);
        }
        #pragma unroll
        for (int t = 0; t < 4; t++)
            acc[t] = __builtin_amdgcn_mfma_f32_16x16x32_bf16(pk, vcur[t], acc[t], 0, 0, 0);
        #pragma unroll
        for (int t = 0; t < 4; t++) vcur[t] = vnxt[t];
    }
    lsum += __shfl_xor(lsum, 16);
    lsum += __shfl_xor(lsum, 32);
    if (lh == 0) lsums[w][lm] = lsum;
    #pragma unroll
    for (int t = 0; t < 4; t++)
        #pragma unroll
        for (int r = 0; r < 4; r++)
            accs[w][qrow[r]][t*16 + vcol[r]] = acc[t][r];
    __syncthreads();
    #pragma unroll
    for (int rr = 0; rr < 2; rr++){
        int row = w * 2 + rr;
        float den = 0.f, v = 0.f;
        #pragma unroll
        for (int q = 0; q < 8; q++){ den += lsums[q][row]; v += accs[q][row][l]; }
        out2[(size_t)(i0 + row) * NCLSD + l] = v / den;
    }
}

// ---------------- row-wise log_softmax over 64 classes ----------------
__global__ void k_logsoftmax(const float* __restrict__ out2, float* __restrict__ out){
    int w = threadIdx.x >> 6, l = threadIdx.x & 63;
    int row = blockIdx.x * 4 + w;
    float v = out2[(size_t)row * NCLSD + l];
    float mx = v;
    #pragma unroll
    for (int o = 32; o; o >>= 1) mx = fmaxf(mx, __shfl_xor(mx, o));
    float ex = __expf(v - mx);
    #pragma unroll
    for (int o = 32; o; o >>= 1) ex += __shfl_xor(ex, o);
    out[(size_t)row * NCLSD + l] = v - mx - logf(ex);
}

// ---------------- launch ----------------
extern "C" void kernel_launch(void* const* d_in, const int* in_sizes, int n_in,
                              void* d_out, int out_size, void* d_ws, size_t ws_size,
                              hipStream_t stream){
    const float* X   = (const float*)d_in[0];
    const int*   adj = (const int*)d_in[1];
    const float* Wg  = (const float*)d_in[2];
    const float* ag  = (const float*)d_in[3];
    const float* Wt  = (const float*)d_in[4];
    const float* at  = (const float*)d_in[5];
    const float* Wo  = (const float*)d_in[6];
    const float* ao  = (const float*)d_in[7];
    float* out = (float*)d_out;

    char* ws = (char*)d_ws;
    size_t off = 0;
    auto take = [&](size_t n){ char* p = ws + off; off = (off + n + 255) & ~(size_t)255; return p; };
    u64_t*    maskb = (u64_t*)take((size_t)NNODE * NMSK * 8);
    ushort_t* VF    = (ushort_t*)take((size_t)HIDD * NNODE * 2);   // fragment layout Wh1
    float*    res   = (float*)take((size_t)NNODE * HIDD * 4);
    float*    Wh2   = (float*)take((size_t)NNODE * NCLSD * 4);
    ushort_t* VF2   = (ushort_t*)take((size_t)NCLSD * NNODE * 2);  // fragment layout Wh2
    ushort_t* XF    = (ushort_t*)take((size_t)NNODE * FEATD * 2);  // fragment layout X
    ushort_t* WgF   = (ushort_t*)take((size_t)FEATD * HIDD * 2);   // fragment layout Wg
    ushort_t* WoF   = (ushort_t*)take((size_t)HIDD * NCLSD * 2);   // fragment layout Wo
    float* e1v  = (float*)take(NNODE * 4);
    float* e2v  = (float*)take(NNODE * 4);
    float* t1v  = (float*)take(NNODE * 4);
    float* t2v  = (float*)take(NNODE * 4);
    float* o1v  = (float*)take(NNODE * 4);
    float* o2v  = (float*)take(NNODE * 4);
    float* wg1  = (float*)take(FEATD * 4);
    float* wg2  = (float*)take(FEATD * 4);
    float* wt1  = (float*)take(HIDD * 4);
    float* wt2  = (float*)take(HIDD * 4);
    float* scal = (float*)take(256);
    float* e2m = scal, * t2m = scal + 1, * o2m = scal + 2;
    float* out2 = Wh2;   // alias: gat2 reads only VF2/vectors

    // P fragment buffer (allocated last; only used if ws is big enough)
    size_t pbytes = (size_t)NNODE * NNODE * 2;
    bool bigws = (off + pbytes + NNODE * 4 + 4096) <= ws_size;
    ushort_t* Pbuf  = bigws ? (ushort_t*)take(pbytes) : nullptr;
    float*    lsumv = bigws ? (float*)take(pbytes ? NNODE * 4 : 0) : nullptr;

    // weight prep
    k_wofrag<<<dim3(((NCLSD/16)*NKTX*64 + 255)/256), dim3(256), 0, stream>>>(Wo, WoF);
    k_fold<<<dim3(FEATD/4), dim3(256), 0, stream>>>(Wg, ag, wg1, wg2, HIDD);
    k_fold<<<dim3(HIDD/4),  dim3(256), 0, stream>>>(Wt, at, wt1, wt2, HIDD);
    // layer-1 scores (exact fp32 fold)
    k_rowvec2_f32<<<dim3(NNODE/4), dim3(256), 0, stream>>>(X, wg1, wg2, e1v, e2v, FEATD);
    k_max<<<dim3(1), dim3(1024), 0, stream>>>(e2v, NNODE, e2m);
    // fragmentize inputs + Wh1 via MFMA (coalesced)
    k_xfrag<<<dim3(NNODE/16), dim3(256), 0, stream>>>(X, XF);
    k_wgfrag<<<dim3(((HIDD/16)*NKTX*64 + 255)/256), dim3(256), 0, stream>>>(Wg, WgF);
    k_gemm_xw<<<dim3(NNODE/16), dim3(512), 0, stream>>>(XF, WgF, VF);
    // GAT layer 1 (pgen reads adj directly + emits byte mask for gat2)
    if (bigws){
        k_pgen<<<dim3(NNODE/16), dim3(256), 0, stream>>>(adj, e1v, e2v, e2m, Pbuf, lsumv, (u8_t*)maskb);
        k_gat1g<<<dim3(NNODE/64 * 8), dim3(256), 0, stream>>>(Pbuf, lsumv, VF, res);
    } else {
        k_adjmask<<<dim3(2048), dim3(256), 0, stream>>>(adj, maskb);
        k_gat1<<<dim3(NNODE/16 * 2), dim3(256), 0, stream>>>(maskb, e1v, e2v, e2m, VF, res);
    }
    // tree scores via fold
    k_rowvec2_f32<<<dim3(NNODE/4), dim3(256), 0, stream>>>(res, wt1, wt2, t1v, t2v, HIDD);
    k_max<<<dim3(1), dim3(1024), 0, stream>>>(t2v, NNODE, t2m);
    // layer-2 prep (MFMA; emits Wh2 fp32 + fragment VF2)
    k_gemm_out<<<dim3(NNODE/64), dim3(256), 0, stream>>>(res, WoF, Wh2, VF2);
    k_rowvec2_f32<<<dim3(NNODE/4), dim3(256), 0, stream>>>(Wh2, ao, ao + NCLSD, o1v, o2v, NCLSD);
    k_max<<<dim3(1), dim3(1024), 0, stream>>>(o2v, NNODE, o2m);
    // GAT layer 2 + log_softmax
    k_gat2<<<dim3(NNODE/16), dim3(512), 0, stream>>>(maskb, o1v, o2v, t1v, t2v, o2m, t2m, VF2, out2);
    k_logsoftmax<<<dim3(NNODE/4), dim3(256), 0, stream>>>(out2, out);
}

// Round 18
// 273.143 us; speedup vs baseline: 1.4953x; 1.0648x over previous
//
#include <hip/hip_runtime.h>

#define NNODE 6144
#define FEATD 512
#define HIDD  512
#define NCLSD 64
#define NMSK  (NNODE/64)   // 96 mask words per row
#define NKT   (NNODE/32)   // 192 k-tiles (node dim)
#define NKTX  (FEATD/32)   // 16 k-tiles (feature dim)
#define LALPHA 0.2f

typedef unsigned short ushort_t;
typedef unsigned char u8_t;
typedef unsigned long long u64_t;
typedef short bf16x8 __attribute__((ext_vector_type(8)));
typedef float f32x4 __attribute__((ext_vector_type(4)));

__device__ __forceinline__ float lrelu(float x){ return x > 0.f ? x : LALPHA * x; }

__device__ __forceinline__ ushort_t f2b(float x){
    union { float f; unsigned u; } v; v.f = x;
    unsigned r = v.u + 0x7fffu + ((v.u >> 16) & 1u);
    return (ushort_t)(r >> 16);
}
__device__ __forceinline__ float b2f(ushort_t u){
    union { unsigned u; float f; } v; v.u = ((unsigned)u) << 16; return v.f;
}

// Runtime C/D-layout calibration (round-8 validated)
__device__ __forceinline__ void calib_cd(int lm, int* qrow, int* vcol){
    bf16x8 ai, as;
    ushort_t vi = f2b((float)(lm + 1));
    ushort_t vs = f2b(0.03125f);
    #pragma unroll
    for (int e = 0; e < 8; e++){ ((ushort_t*)&ai)[e] = vi; ((ushort_t*)&as)[e] = vs; }
    f32x4 z = {0.f, 0.f, 0.f, 0.f};
    f32x4 d1 = __builtin_amdgcn_mfma_f32_16x16x32_bf16(ai, as, z, 0, 0, 0);
    f32x4 d2 = __builtin_amdgcn_mfma_f32_16x16x32_bf16(as, ai, z, 0, 0, 0);
    #pragma unroll
    for (int r = 0; r < 4; r++){
        qrow[r] = (int)(d1[r] + 0.5f) - 1;
        vcol[r] = (int)(d2[r] + 0.5f) - 1;
    }
}

// ---------------- adj (int32) -> bitmask (fallback path only) ----------------
__global__ void k_adjmask(const int* __restrict__ adj, u64_t* __restrict__ mask){
    int lane = threadIdx.x & 63;
    size_t wid = ((size_t)blockIdx.x * blockDim.x + threadIdx.x) >> 6;
    size_t nw = (size_t)NNODE * NNODE / 64;
    size_t stride = ((size_t)gridDim.x * blockDim.x) >> 6;
    for (size_t q = wid; q < nw; q += stride){
        int a = adj[q * 64 + lane];
        u64_t b = __ballot(a > 0);
        if (lane == 0) mask[q] = b;
    }
}

// out1[r]=W[r]·a[0:K]; out2[r]=W[r]·a[K:2K]  (one wave per row)
__global__ void k_fold(const float* __restrict__ W, const float* __restrict__ a,
                       float* __restrict__ out1, float* __restrict__ out2, int K){
    int row  = (blockIdx.x * blockDim.x + threadIdx.x) >> 6;
    int lane = threadIdx.x & 63;
    const float* wr = W + (size_t)row * K;
    float s1 = 0.f, s2 = 0.f;
    for (int c = lane; c < K; c += 64){ float w = wr[c]; s1 += w * a[c]; s2 += w * a[K + c]; }
    #pragma unroll
    for (int m = 32; m; m >>= 1){ s1 += __shfl_xor(s1, m); s2 += __shfl_xor(s2, m); }
    if (lane == 0){ out1[row] = s1; out2[row] = s2; }
}

// ---------------- o1/o2 = A @ {v1,v2}  (one wave per row) ----------------
__global__ void k_rowvec2_f32(const float* __restrict__ A, const float* __restrict__ v1,
                              const float* __restrict__ v2, float* __restrict__ o1,
                              float* __restrict__ o2, int K){
    int row  = (blockIdx.x * blockDim.x + threadIdx.x) >> 6;
    int lane = threadIdx.x & 63;
    const float* r = A + (size_t)row * K;
    float s1 = 0.f, s2 = 0.f;
    for (int c = lane; c < K; c += 64){ float x = r[c]; s1 += x * v1[c]; s2 += x * v2[c]; }
    #pragma unroll
    for (int m = 32; m; m >>= 1){ s1 += __shfl_xor(s1, m); s2 += __shfl_xor(s2, m); }
    if (lane == 0){ o1[row] = s1; o2[row] = s2; }
}

// ---------------- *out = max(x[0..n)) ----------------
__global__ void k_max(const float* __restrict__ x, int n, float* __restrict__ out){
    __shared__ float sm[16];
    float m = -3.0e38f;
    for (int i = threadIdx.x; i < n; i += blockDim.x) m = fmaxf(m, x[i]);
    #pragma unroll
    for (int s = 32; s; s >>= 1) m = fmaxf(m, __shfl_xor(m, s));
    if ((threadIdx.x & 63) == 0) sm[threadIdx.x >> 6] = m;
    __syncthreads();
    if (threadIdx.x == 0){
        float mm = sm[0];
        for (int i = 1; i < (int)(blockDim.x >> 6); i++) mm = fmaxf(mm, sm[i]);
        *out = mm;
    }
}

// ---------------- X -> XF bf16 fragment layout ----------------
__global__ __launch_bounds__(256) void k_xfrag(const float* __restrict__ X,
                                               ushort_t* __restrict__ XF){
    int ri = blockIdx.x;
    int tid = threadIdx.x;
    int r = tid >> 4, q = tid & 15;
    const float* xp = X + (size_t)(ri * 16 + r) * FEATD;
    ushort_t* xb = XF + (size_t)ri * NKTX * 512;
    for (int j0 = 0; j0 < FEATD; j0 += 128){
        int j = j0 + q * 8;
        float4 fA = *(const float4*)(xp + j);
        float4 fB = *(const float4*)(xp + j + 4);
        float xa[8] = {fA.x, fA.y, fA.z, fA.w, fB.x, fB.y, fB.z, fB.w};
        bf16x8 pk;
        #pragma unroll
        for (int e = 0; e < 8; e++) ((ushort_t*)&pk)[e] = f2b(xa[e]);
        int ki = j >> 5;
        int lh = (j >> 3) & 3;
        *(bf16x8*)(xb + ((size_t)ki * 512 + (size_t)(r + (lh << 4)) * 8)) = pk;
    }
}

// ---------------- Wg -> WgF fragment layout (B-operand) ----------------
__global__ __launch_bounds__(256) void k_wgfrag(const float* __restrict__ Wg,
                                                ushort_t* __restrict__ WgF){
    int gid = blockIdx.x * 256 + threadIdx.x;
    if (gid >= (HIDD/16) * NKTX * 64) return;
    int l = gid & 63, unit = gid >> 6;
    int ci = unit / NKTX, ki = unit - ci * NKTX;
    int lm = l & 15, lh = l >> 4;
    bf16x8 pk;
    #pragma unroll
    for (int e = 0; e < 8; e++)
        ((ushort_t*)&pk)[e] = f2b(Wg[(size_t)(ki*32 + lh*8 + e) * HIDD + ci*16 + lm]);
    *(bf16x8*)(WgF + (size_t)unit * 512 + (size_t)l * 8) = pk;
}

// ---------------- Wo -> WoF fragment layout (B-operand for gemm_out) ----------------
__global__ __launch_bounds__(256) void k_wofrag(const float* __restrict__ Wo,
                                                ushort_t* __restrict__ WoF){
    int gid = blockIdx.x * 256 + threadIdx.x;
    if (gid >= (NCLSD/16) * NKTX * 64) return;
    int l = gid & 63, unit = gid >> 6;
    int ci = unit / NKTX, ki = unit - ci * NKTX;
    int lm = l & 15, lh = l >> 4;
    bf16x8 pk;
    #pragma unroll
    for (int e = 0; e < 8; e++)
        ((ushort_t*)&pk)[e] = f2b(Wo[(size_t)(ki*32 + lh*8 + e) * NCLSD + ci*16 + lm]);
    *(bf16x8*)(WoF + (size_t)unit * 512 + (size_t)l * 8) = pk;
}

// ---------------- Wh1 = X @ Wg via MFMA -> VF fragments ----------------
__global__ __launch_bounds__(512) void k_gemm_xw(const ushort_t* __restrict__ XF,
        const ushort_t* __restrict__ WgF, ushort_t* __restrict__ VF){
    int ri = blockIdx.x;
    int i0 = ri * 16;
    int w = threadIdx.x >> 6, l = threadIdx.x & 63, lm = l & 15;
    int c0 = w * 64;
    int qrow[4], vcol[4];
    calib_cd(lm, qrow, vcol);
    f32x4 acc[4] = {};
    const ushort_t* Ap = XF + (size_t)ri * NKTX * 512 + l * 8;
    const ushort_t* Bp[4];
    #pragma unroll
    for (int t = 0; t < 4; t++)
        Bp[t] = WgF + (size_t)((c0 >> 4) + t) * NKTX * 512 + l * 8;
    for (int ki = 0; ki < NKTX; ki++){
        bf16x8 af = *(const bf16x8*)(Ap + (size_t)ki * 512);
        #pragma unroll
        for (int t = 0; t < 4; t++){
            bf16x8 bf = *(const bf16x8*)(Bp[t] + (size_t)ki * 512);
            acc[t] = __builtin_amdgcn_mfma_f32_16x16x32_bf16(af, bf, acc[t], 0, 0, 0);
        }
    }
    #pragma unroll
    for (int t = 0; t < 4; t++){
        int ci = (c0 >> 4) + t;
        #pragma unroll
        for (int r = 0; r < 4; r++){
            int node = i0 + qrow[r];
            size_t vo = ((size_t)ci * NKT + (node >> 5)) * 512
                      + (size_t)(vcol[r] + ((node >> 3) & 3) * 16) * 8 + (node & 7);
            VF[vo] = f2b(acc[t][r]);
        }
    }
}

// ---------------- Wh2 = res @ Wo via MFMA; emits fp32 Wh2 + fragment VF2 ----------------
__global__ __launch_bounds__(256) void k_gemm_out(const float* __restrict__ res,
        const ushort_t* __restrict__ WoF, float* __restrict__ Wh2, ushort_t* __restrict__ VF2){
    int w = threadIdx.x >> 6, l = threadIdx.x & 63, lm = l & 15, lh = l >> 4;
    int i0 = blockIdx.x * 64 + w * 16;
    int qrow[4], vcol[4];
    calib_cd(lm, qrow, vcol);
    f32x4 acc[4] = {};
    const float* ap = res + (size_t)(i0 + lm) * HIDD + lh * 8;
    for (int k0 = 0; k0 < HIDD; k0 += 32){
        int ki = k0 >> 5;
        float4 x0 = *(const float4*)(ap + k0);
        float4 x1 = *(const float4*)(ap + k0 + 4);
        float xa[8] = {x0.x, x0.y, x0.z, x0.w, x1.x, x1.y, x1.z, x1.w};
        bf16x8 af;
        #pragma unroll
        for (int e = 0; e < 8; e++) ((ushort_t*)&af)[e] = f2b(xa[e]);
        #pragma unroll
        for (int t = 0; t < 4; t++){
            bf16x8 bf = *(const bf16x8*)(WoF + (size_t)(t * NKTX + ki) * 512 + l * 8);
            acc[t] = __builtin_amdgcn_mfma_f32_16x16x32_bf16(af, bf, acc[t], 0, 0, 0);
        }
    }
    #pragma unroll
    for (int t = 0; t < 4; t++){
        #pragma unroll
        for (int r = 0; r < 4; r++){
            int node = i0 + qrow[r], col = t*16 + vcol[r];
            float v = acc[t][r];
            Wh2[(size_t)node * NCLSD + col] = v;
            size_t vo = ((size_t)t * NKT + (node >> 5)) * 512
                      + (size_t)(vcol[r] + ((node >> 3) & 3) * 16) * 8 + (node & 7);
            VF2[vo] = f2b(v);
        }
    }
}

// ---------------- P-gen v2: reads adj directly, emits PF + byte mask + row sums ----------------
__global__ __launch_bounds__(256) void k_pgen(const int* __restrict__ adj,
        const float* __restrict__ e1, const float* __restrict__ e2,
        const float* __restrict__ e2max, ushort_t* __restrict__ PF,
        float* __restrict__ lsum, u8_t* __restrict__ mask8){
    __shared__ float e2s[NNODE];
    int ri = blockIdx.x;
    int i0 = ri * 16;
    int tid = threadIdx.x;
    int r = tid >> 4, q = tid & 15;
    for (int k = tid; k < NNODE; k += 256) e2s[k] = e2[k];
    __syncthreads();
    float e1i = e1[i0 + r];
    float M = lrelu(e1i + *e2max);   // exact upper bound (softmax shift-invariant)
    float rsum = 0.f;
    ushort_t* pfb = PF + (size_t)ri * NKT * 512;
    const int* adjp = adj + (size_t)(i0 + r) * NNODE;
    u8_t* mrow = mask8 + (size_t)(i0 + r) * (NMSK * 8);
    for (int j0 = 0; j0 < NNODE; j0 += 128){
        int j = j0 + q * 8;
        int4 a0 = *(const int4*)(adjp + j);
        int4 a1 = *(const int4*)(adjp + j + 4);
        int av[8] = {a0.x, a0.y, a0.z, a0.w, a1.x, a1.y, a1.z, a1.w};
        float4 fA = *(const float4*)&e2s[j];
        float4 fB = *(const float4*)&e2s[j + 4];
        float ea[8] = {fA.x, fA.y, fA.z, fA.w, fB.x, fB.y, fB.z, fB.w};
        bf16x8 pk;
        unsigned byte = 0;
        #pragma unroll
        for (int e = 0; e < 8; e++){
            int bit = av[e] > 0;
            byte |= (unsigned)bit << e;
            float p = bit ? __expf(lrelu(e1i + ea[e]) - M) : 0.f;
            ushort_t pb = f2b(p);
            ((ushort_t*)&pk)[e] = pb;
            rsum += b2f(pb);
        }
        mrow[j >> 3] = (u8_t)byte;
        int ki = j >> 5;
        int lh = (j >> 3) & 3;
        *(bf16x8*)(pfb + ((size_t)ki * 512 + (size_t)(r + (lh << 4)) * 8)) = pk;
    }
    #pragma unroll
    for (int o = 8; o; o >>= 1) rsum += __shfl_xor(rsum, o);
    if (q == 0) lsum[i0 + r] = rsum;
}

// ---------------- GAT1 GEMM + XCD-affinity swizzle ----------------
// bid -> xcd = bid&7 (HW round-robin); the 8 c8-blocks of one rg land on ONE
// XCD, temporally adjacent -> P row-block (786KB) fetched once into that L2.
__global__ __launch_bounds__(256) void k_gat1g(const ushort_t* __restrict__ PF,
        const float* __restrict__ lsum, const ushort_t* __restrict__ VF,
        float* __restrict__ res){
    int bid = blockIdx.x;
    int xcd = bid & 7;
    int k   = bid >> 3;
    int c8  = k & 7;
    int rg  = (k >> 3) * 8 + xcd;
    int tid = threadIdx.x;
    int w = tid >> 6, l = tid & 63, lm = l & 15;
    int ri = rg * 4 + w;
    int i0 = ri * 16;
    int cbase = c8 * 64;
    int qrow[4], vcol[4];
    calib_cd(lm, qrow, vcol);
    f32x4 acc[4] = {};
    const ushort_t* Ap = PF + (size_t)ri * NKT * 512 + l * 8;
    const ushort_t* Vp[4];
    #pragma unroll
    for (int t = 0; t < 4; t++)
        Vp[t] = VF + (size_t)(c8 * 4 + t) * NKT * 512 + l * 8;
    bf16x8 a0c = *(const bf16x8*)(Ap);
    bf16x8 a1c = *(const bf16x8*)(Ap + 512);
    bf16x8 vc[4][2], vn[4][2], a0n = {}, a1n = {};
    #pragma unroll
    for (int t = 0; t < 4; t++){
        vc[t][0] = *(const bf16x8*)(Vp[t]);
        vc[t][1] = *(const bf16x8*)(Vp[t] + 512);
    }
    for (int s = 0; s < NKT/2; s++){
        size_t nb = (size_t)(s + 1) * 1024;
        if (s + 1 < NKT/2){
            a0n = *(const bf16x8*)(Ap + nb);
            a1n = *(const bf16x8*)(Ap + nb + 512);
            #pragma unroll
            for (int t = 0; t < 4; t++){
                vn[t][0] = *(const bf16x8*)(Vp[t] + nb);
                vn[t][1] = *(const bf16x8*)(Vp[t] + nb + 512);
            }
        }
        #pragma unroll
        for (int t = 0; t < 4; t++){
            acc[t] = __builtin_amdgcn_mfma_f32_16x16x32_bf16(a0c, vc[t][0], acc[t], 0, 0, 0);
            acc[t] = __builtin_amdgcn_mfma_f32_16x16x32_bf16(a1c, vc[t][1], acc[t], 0, 0, 0);
        }
        a0c = a0n; a1c = a1n;
        #pragma unroll
        for (int t = 0; t < 4; t++){ vc[t][0] = vn[t][0]; vc[t][1] = vn[t][1]; }
    }
    float den[4];
    #pragma unroll
    for (int r = 0; r < 4; r++) den[r] = lsum[i0 + qrow[r]];
    #pragma unroll
    for (int t = 0; t < 4; t++){
        #pragma unroll
        for (int r = 0; r < 4; r++){
            int row = qrow[r];
            int col = cbase + t*16 + vcol[r];
            float v = acc[t][r] / den[r];
            v = v > 0.f ? v : expm1f(v);   // elu
            res[(size_t)(i0 + row) * HIDD + col] = v;
        }
    }
}

// ---------------- GAT layer 1 fallback (register P, VF layout) ----------------
__global__ __launch_bounds__(256) void k_gat1(const u64_t* __restrict__ mask,
        const float* __restrict__ e1, const float* __restrict__ e2,
        const float* __restrict__ e2max,
        const ushort_t* __restrict__ VF, float* __restrict__ res){
    __shared__ __align__(16) float e2s[NNODE];
    __shared__ u64_t msk[16][NMSK + 1];
    int bid = blockIdx.x;
    int b8 = bid & 7, a = bid >> 3;
    int ch = b8 >> 2;
    int rg = a * 4 + (b8 & 3);
    int i0 = rg * 16;
    int tid = threadIdx.x;
    int w = tid >> 6, l = tid & 63, lm = l & 15, lh = l >> 4;
    int cbase = ch * 256 + w * 64;
    int qrow[4], vcol[4];
    calib_cd(lm, qrow, vcol);
    for (int k = tid; k < NNODE; k += 256) e2s[k] = e2[k];
    for (int k = tid; k < 16 * NMSK; k += 256) msk[k / NMSK][k % NMSK] = mask[(size_t)i0 * NMSK + k];
    __syncthreads();
    float e1i = e1[i0 + lm];
    float M = lrelu(e1i + *e2max);
    float lsum = 0.f;
    f32x4 acc[4] = {};
    const ushort_t* Vp[4];
    #pragma unroll
    for (int t = 0; t < 4; t++)
        Vp[t] = VF + (size_t)((cbase >> 4) + t) * NKT * 512 + l * 8;
    bf16x8 vc[4][2], vn[4][2];
    #pragma unroll
    for (int t = 0; t < 4; t++)
        #pragma unroll
        for (int h = 0; h < 2; h++) vc[t][h] = *(const bf16x8*)(Vp[t] + h * 512);
    for (int j0 = 0; j0 < NNODE; j0 += 64){
        u64_t word = msk[lm][j0 >> 6];
        int jn = j0 + 64;
        if (jn < NNODE){
            size_t nb = (size_t)(jn >> 5) * 512;
            #pragma unroll
            for (int t = 0; t < 4; t++)
                #pragma unroll
                for (int h = 0; h < 2; h++) vn[t][h] = *(const bf16x8*)(Vp[t] + nb + h * 512);
        }
        #pragma unroll
        for (int h = 0; h < 2; h++){
            int jb = j0 + h*32 + lh*8;
            float4 fA = *(const float4*)&e2s[jb];
            float4 fB = *(const float4*)&e2s[jb + 4];
            float ea[8] = {fA.x, fA.y, fA.z, fA.w, fB.x, fB.y, fB.z, fB.w};
            int sh = h*32 + lh*8;
            bf16x8 pk;
            float ls = 0.f;
            #pragma unroll
            for (int e = 0; e < 8; e++){
                float p = ((word >> (sh + e)) & 1ull) ? __expf(lrelu(e1i + ea[e]) - M) : 0.f;
                ushort_t pb = f2b(p);
                ((ushort_t*)&pk)[e] = pb;
                ls += b2f(pb);
            }
            lsum += ls;
            #pragma unroll
            for (int t = 0; t < 4; t++)
                acc[t] = __builtin_amdgcn_mfma_f32_16x16x32_bf16(pk, vc[t][h], acc[t], 0, 0, 0);
        }
        #pragma unroll
        for (int t = 0; t < 4; t++)
            #pragma unroll
            for (int h = 0; h < 2; h++) vc[t][h] = vn[t][h];
    }
    lsum += __shfl_xor(lsum, 16);
    lsum += __shfl_xor(lsum, 32);
    #pragma unroll
    for (int t = 0; t < 4; t++){
        #pragma unroll
        for (int r = 0; r < 4; r++){
            float den = __shfl(lsum, qrow[r]);
            int row = qrow[r];
            int col = cbase + t*16 + vcol[r];
            float v = acc[t][r] / den;
            v = v > 0.f ? v : expm1f(v);
            res[(size_t)(i0 + row) * HIDD + col] = v;
        }
    }
}

// ---------------- GAT layer 2: 8-wave j-split, fragment V2, byte-mask ----------------
#define JSPAN (NNODE/8)
__global__ __launch_bounds__(512) void k_gat2(const u64_t* __restrict__ mask,
        const float* __restrict__ o1, const float* __restrict__ o2,
        const float* __restrict__ t1, const float* __restrict__ t2,
        const float* __restrict__ o2max, const float* __restrict__ t2max,
        const ushort_t* __restrict__ VF2, float* __restrict__ out2){
    __shared__ float accs[8][16][64];
    __shared__ float lsums[8][16];
    __shared__ u64_t msk[16][NMSK + 1];
    int i0 = blockIdx.x * 16;
    int tid = threadIdx.x;
    int w = tid >> 6, l = tid & 63, lm = l & 15, lh = l >> 4;
    for (int k = tid; k < 16 * NMSK; k += 512) msk[k / NMSK][k % NMSK] = mask[(size_t)i0 * NMSK + k];
    __syncthreads();
    int qrow[4], vcol[4];
    calib_cd(lm, qrow, vcol);
    int jbase = w * JSPAN;
    float o1v = o1[i0 + lm], t1v = t1[i0 + lm];
    float M = lrelu(o1v + *o2max) + lrelu(t1v + *t2max);
    float lsum = 0.f;
    f32x4 acc[4] = {};
    const float* o2p = o2 + jbase + lh * 8;
    const float* t2p = t2 + jbase + lh * 8;
    float4 oA = *(const float4*)(o2p), oB = *(const float4*)(o2p + 4);
    float4 tA = *(const float4*)(t2p), tB = *(const float4*)(t2p + 4);
    const u8_t* mrow = (const u8_t*)&msk[lm][0];
    const ushort_t* Vp[4];
    #pragma unroll
    for (int t = 0; t < 4; t++)
        Vp[t] = VF2 + (size_t)t * NKT * 512 + (size_t)(jbase >> 5) * 512 + l * 8;
    bf16x8 vcur[4], vnxt[4];
    #pragma unroll
    for (int t = 0; t < 4; t++) vcur[t] = *(const bf16x8*)(Vp[t]);

    for (int js = 0; js < JSPAN; js += 32){
        unsigned b8v = mrow[(jbase + js + lh * 8) >> 3];
        float oa[8] = {oA.x, oA.y, oA.z, oA.w, oB.x, oB.y, oB.z, oB.w};
        float ta[8] = {tA.x, tA.y, tA.z, tA.w, tB.x, tB.y, tB.z, tB.w};
        bf16x8 pk;
        float ls = 0.f;
        #pragma unroll
        for (int e = 0; e < 8; e++){
            float p = ((b8v >> e) & 1u) ?
                      __expf(lrelu(o1v + oa[e]) + lrelu(t1v + ta[e]) - M) : 0.f;
            ushort_t pb = f2b(p);
            ((ushort_t*)&pk)[e] = pb;
            ls += b2f(pb);
        }
        lsum += ls;
        int jn = js + 32;
        if (jn < JSPAN){
            oA = *(const float4*)(o2p + jn); oB = *(const float4*)(o2p + jn + 4);
            tA = *(const float4*)(t2p + jn); tB = *(const float4*)(t2p + jn + 4);
            #pragma unroll
            for (int t = 0; t < 4; t++)
                vnxt[t] = *(const bf16x8*)(Vp[t] + (size_t)(jn >> 5) * 512);
        }
        #pragma unroll
        for (int t = 0; t < 4; t++)
            acc[t] = __builtin_amdgcn_mfma_f32_16x16x32_bf16(pk, vcur[t], acc[t], 0, 0, 0);
        #pragma unroll
        for (int t = 0; t < 4; t++) vcur[t] = vnxt[t];
    }
    lsum += __shfl_xor(lsum, 16);
    lsum += __shfl_xor(lsum, 32);
    if (lh == 0) lsums[w][lm] = lsum;
    #pragma unroll
    for (int t = 0; t < 4; t++)
        #pragma unroll
        for (int r = 0; r < 4; r++)
            accs[w][qrow[r]][t*16 + vcol[r]] = acc[t][r];
    __syncthreads();
    #pragma unroll
    for (int rr = 0; rr < 2; rr++){
        int row = w * 2 + rr;
        float den = 0.f, v = 0.f;
        #pragma unroll
        for (int q = 0; q < 8; q++){ den += lsums[q][row]; v += accs[q][row][l]; }
        out2[(size_t)(i0 + row) * NCLSD + l] = v / den;
    }
}

// ---------------- row-wise log_softmax over 64 classes ----------------
__global__ void k_logsoftmax(const float* __restrict__ out2, float* __restrict__ out){
    int w = threadIdx.x >> 6, l = threadIdx.x & 63;
    int row = blockIdx.x * 4 + w;
    float v = out2[(size_t)row * NCLSD + l];
    float mx = v;
    #pragma unroll
    for (int o = 32; o; o >>= 1) mx = fmaxf(mx, __shfl_xor(mx, o));
    float ex = __expf(v - mx);
    #pragma unroll
    for (int o = 32; o; o >>= 1) ex += __shfl_xor(ex, o);
    out[(size_t)row * NCLSD + l] = v - mx - logf(ex);
}

// ---------------- launch ----------------
extern "C" void kernel_launch(void* const* d_in, const int* in_sizes, int n_in,
                              void* d_out, int out_size, void* d_ws, size_t ws_size,
                              hipStream_t stream){
    const float* X   = (const float*)d_in[0];
    const int*   adj = (const int*)d_in[1];
    const float* Wg  = (const float*)d_in[2];
    const float* ag  = (const float*)d_in[3];
    const float* Wt  = (const float*)d_in[4];
    const float* at  = (const float*)d_in[5];
    const float* Wo  = (const float*)d_in[6];
    const float* ao  = (const float*)d_in[7];
    float* out = (float*)d_out;

    char* ws = (char*)d_ws;
    size_t off = 0;
    auto take = [&](size_t n){ char* p = ws + off; off = (off + n + 255) & ~(size_t)255; return p; };
    u64_t*    maskb = (u64_t*)take((size_t)NNODE * NMSK * 8);
    ushort_t* VF    = (ushort_t*)take((size_t)HIDD * NNODE * 2);   // fragment layout Wh1
    float*    res   = (float*)take((size_t)NNODE * HIDD * 4);
    float*    Wh2   = (float*)take((size_t)NNODE * NCLSD * 4);
    ushort_t* VF2   = (ushort_t*)take((size_t)NCLSD * NNODE * 2);  // fragment layout Wh2
    ushort_t* XF    = (ushort_t*)take((size_t)NNODE * FEATD * 2);  // fragment layout X
    ushort_t* WgF   = (ushort_t*)take((size_t)FEATD * HIDD * 2);   // fragment layout Wg
    ushort_t* WoF   = (ushort_t*)take((size_t)HIDD * NCLSD * 2);   // fragment layout Wo
    float* e1v  = (float*)take(NNODE * 4);
    float* e2v  = (float*)take(NNODE * 4);
    float* t1v  = (float*)take(NNODE * 4);
    float* t2v  = (float*)take(NNODE * 4);
    float* o1v  = (float*)take(NNODE * 4);
    float* o2v  = (float*)take(NNODE * 4);
    float* wg1  = (float*)take(FEATD * 4);
    float* wg2  = (float*)take(FEATD * 4);
    float* wt1  = (float*)take(HIDD * 4);
    float* wt2  = (float*)take(HIDD * 4);
    float* scal = (float*)take(256);
    float* e2m = scal, * t2m = scal + 1, * o2m = scal + 2;
    float* out2 = Wh2;   // alias: gat2 reads only VF2/vectors

    // P fragment buffer (allocated last; only used if ws is big enough)
    size_t pbytes = (size_t)NNODE * NNODE * 2;
    bool bigws = (off + pbytes + NNODE * 4 + 4096) <= ws_size;
    ushort_t* Pbuf  = bigws ? (ushort_t*)take(pbytes) : nullptr;
    float*    lsumv = bigws ? (float*)take(NNODE * 4) : nullptr;

    // weight prep
    k_wofrag<<<dim3(((NCLSD/16)*NKTX*64 + 255)/256), dim3(256), 0, stream>>>(Wo, WoF);
    k_fold<<<dim3(FEATD/4), dim3(256), 0, stream>>>(Wg, ag, wg1, wg2, HIDD);
    k_fold<<<dim3(HIDD/4),  dim3(256), 0, stream>>>(Wt, at, wt1, wt2, HIDD);
    // layer-1 scores (exact fp32 fold)
    k_rowvec2_f32<<<dim3(NNODE/4), dim3(256), 0, stream>>>(X, wg1, wg2, e1v, e2v, FEATD);
    k_max<<<dim3(1), dim3(1024), 0, stream>>>(e2v, NNODE, e2m);
    // fragmentize inputs + Wh1 via MFMA (coalesced)
    k_xfrag<<<dim3(NNODE/16), dim3(256), 0, stream>>>(X, XF);
    k_wgfrag<<<dim3(((HIDD/16)*NKTX*64 + 255)/256), dim3(256), 0, stream>>>(Wg, WgF);
    k_gemm_xw<<<dim3(NNODE/16), dim3(512), 0, stream>>>(XF, WgF, VF);
    // GAT layer 1 (pgen reads adj directly + emits byte mask for gat2)
    if (bigws){
        k_pgen<<<dim3(NNODE/16), dim3(256), 0, stream>>>(adj, e1v, e2v, e2m, Pbuf, lsumv, (u8_t*)maskb);
        k_gat1g<<<dim3(NNODE/64 * 8), dim3(256), 0, stream>>>(Pbuf, lsumv, VF, res);
    } else {
        k_adjmask<<<dim3(2048), dim3(256), 0, stream>>>(adj, maskb);
        k_gat1<<<dim3(NNODE/16 * 2), dim3(256), 0, stream>>>(maskb, e1v, e2v, e2m, VF, res);
    }
    // tree scores via fold
    k_rowvec2_f32<<<dim3(NNODE/4), dim3(256), 0, stream>>>(res, wt1, wt2, t1v, t2v, HIDD);
    k_max<<<dim3(1), dim3(1024), 0, stream>>>(t2v, NNODE, t2m);
    // layer-2 prep (MFMA; emits Wh2 fp32 + fragment VF2)
    k_gemm_out<<<dim3(NNODE/64), dim3(256), 0, stream>>>(res, WoF, Wh2, VF2);
    k_rowvec2_f32<<<dim3(NNODE/4), dim3(256), 0, stream>>>(Wh2, ao, ao + NCLSD, o1v, o2v, NCLSD);
    k_max<<<dim3(1), dim3(1024), 0, stream>>>(o2v, NNODE, o2m);
    // GAT layer 2 + log_softmax
    k_gat2<<<dim3(NNODE/16), dim3(512), 0, stream>>>(maskb, o1v, o2v, t1v, t2v, o2m, t2m, VF2, out2);
    k_logsoftmax<<<dim3(NNODE/4), dim3(256), 0, stream>>>(out2, out);
}

// Round 19
// 267.934 us; speedup vs baseline: 1.5243x; 1.0194x over previous
//
#include <hip/hip_runtime.h>

#define NNODE 6144
#define FEATD 512
#define HIDD  512
#define NCLSD 64
#define NMSK  (NNODE/64)   // 96 mask words per row
#define NKT   (NNODE/32)   // 192 k-tiles (node dim)
#define NKTX  (FEATD/32)   // 16 k-tiles (feature dim)
#define LALPHA 0.2f

typedef unsigned short ushort_t;
typedef unsigned char u8_t;
typedef unsigned long long u64_t;
typedef short bf16x8 __attribute__((ext_vector_type(8)));
typedef float f32x4 __attribute__((ext_vector_type(4)));

__device__ __forceinline__ float lrelu(float x){ return x > 0.f ? x : LALPHA * x; }

__device__ __forceinline__ ushort_t f2b(float x){
    union { float f; unsigned u; } v; v.f = x;
    unsigned r = v.u + 0x7fffu + ((v.u >> 16) & 1u);
    return (ushort_t)(r >> 16);
}
__device__ __forceinline__ float b2f(ushort_t u){
    union { unsigned u; float f; } v; v.u = ((unsigned)u) << 16; return v.f;
}

// Runtime C/D-layout calibration (round-8 validated)
__device__ __forceinline__ void calib_cd(int lm, int* qrow, int* vcol){
    bf16x8 ai, as;
    ushort_t vi = f2b((float)(lm + 1));
    ushort_t vs = f2b(0.03125f);
    #pragma unroll
    for (int e = 0; e < 8; e++){ ((ushort_t*)&ai)[e] = vi; ((ushort_t*)&as)[e] = vs; }
    f32x4 z = {0.f, 0.f, 0.f, 0.f};
    f32x4 d1 = __builtin_amdgcn_mfma_f32_16x16x32_bf16(ai, as, z, 0, 0, 0);
    f32x4 d2 = __builtin_amdgcn_mfma_f32_16x16x32_bf16(as, ai, z, 0, 0, 0);
    #pragma unroll
    for (int r = 0; r < 4; r++){
        qrow[r] = (int)(d1[r] + 0.5f) - 1;
        vcol[r] = (int)(d2[r] + 0.5f) - 1;
    }
}

// ---------------- adj (int32) -> bitmask (fallback path only) ----------------
__global__ void k_adjmask(const int* __restrict__ adj, u64_t* __restrict__ mask){
    int lane = threadIdx.x & 63;
    size_t wid = ((size_t)blockIdx.x * blockDim.x + threadIdx.x) >> 6;
    size_t nw = (size_t)NNODE * NNODE / 64;
    size_t stride = ((size_t)gridDim.x * blockDim.x) >> 6;
    for (size_t q = wid; q < nw; q += stride){
        int a = adj[q * 64 + lane];
        u64_t b = __ballot(a > 0);
        if (lane == 0) mask[q] = b;
    }
}

// out1[r]=W[r]·a[0:K]; out2[r]=W[r]·a[K:2K]  (one wave per row)
__global__ void k_fold(const float* __restrict__ W, const float* __restrict__ a,
                       float* __restrict__ out1, float* __restrict__ out2, int K){
    int row  = (blockIdx.x * blockDim.x + threadIdx.x) >> 6;
    int lane = threadIdx.x & 63;
    const float* wr = W + (size_t)row * K;
    float s1 = 0.f, s2 = 0.f;
    for (int c = lane; c < K; c += 64){ float w = wr[c]; s1 += w * a[c]; s2 += w * a[K + c]; }
    #pragma unroll
    for (int m = 32; m; m >>= 1){ s1 += __shfl_xor(s1, m); s2 += __shfl_xor(s2, m); }
    if (lane == 0){ out1[row] = s1; out2[row] = s2; }
}

// ---------------- o1/o2 = A @ {v1,v2}  (one wave per row) ----------------
__global__ void k_rowvec2_f32(const float* __restrict__ A, const float* __restrict__ v1,
                              const float* __restrict__ v2, float* __restrict__ o1,
                              float* __restrict__ o2, int K){
    int row  = (blockIdx.x * blockDim.x + threadIdx.x) >> 6;
    int lane = threadIdx.x & 63;
    const float* r = A + (size_t)row * K;
    float s1 = 0.f, s2 = 0.f;
    for (int c = lane; c < K; c += 64){ float x = r[c]; s1 += x * v1[c]; s2 += x * v2[c]; }
    #pragma unroll
    for (int m = 32; m; m >>= 1){ s1 += __shfl_xor(s1, m); s2 += __shfl_xor(s2, m); }
    if (lane == 0){ o1[row] = s1; o2[row] = s2; }
}

// ---------------- *out = max(x[0..n)) ----------------
__global__ void k_max(const float* __restrict__ x, int n, float* __restrict__ out){
    __shared__ float sm[16];
    float m = -3.0e38f;
    for (int i = threadIdx.x; i < n; i += blockDim.x) m = fmaxf(m, x[i]);
    #pragma unroll
    for (int s = 32; s; s >>= 1) m = fmaxf(m, __shfl_xor(m, s));
    if ((threadIdx.x & 63) == 0) sm[threadIdx.x >> 6] = m;
    __syncthreads();
    if (threadIdx.x == 0){
        float mm = sm[0];
        for (int i = 1; i < (int)(blockDim.x >> 6); i++) mm = fmaxf(mm, sm[i]);
        *out = mm;
    }
}

// ---------------- fused: X -> XF fragments + e1/e2 scores (single X pass) ----------------
__global__ __launch_bounds__(256) void k_xprep(const float* __restrict__ X,
        const float* __restrict__ wg1, const float* __restrict__ wg2,
        ushort_t* __restrict__ XF, float* __restrict__ e1, float* __restrict__ e2){
    __shared__ float w1s[FEATD], w2s[FEATD];
    int ri = blockIdx.x;
    int tid = threadIdx.x;
    int r = tid >> 4, q = tid & 15;
    for (int k = tid; k < FEATD; k += 256){ w1s[k] = wg1[k]; w2s[k] = wg2[k]; }
    __syncthreads();
    const float* xp = X + (size_t)(ri * 16 + r) * FEATD;
    ushort_t* xb = XF + (size_t)ri * NKTX * 512;
    float s1 = 0.f, s2 = 0.f;
    for (int j0 = 0; j0 < FEATD; j0 += 128){
        int j = j0 + q * 8;
        float4 fA = *(const float4*)(xp + j);
        float4 fB = *(const float4*)(xp + j + 4);
        float xa[8] = {fA.x, fA.y, fA.z, fA.w, fB.x, fB.y, fB.z, fB.w};
        bf16x8 pk;
        #pragma unroll
        for (int e = 0; e < 8; e++){
            ((ushort_t*)&pk)[e] = f2b(xa[e]);
            s1 += xa[e] * w1s[j + e];
            s2 += xa[e] * w2s[j + e];
        }
        int ki = j >> 5;
        int lh = (j >> 3) & 3;
        *(bf16x8*)(xb + ((size_t)ki * 512 + (size_t)(r + (lh << 4)) * 8)) = pk;
    }
    #pragma unroll
    for (int o = 8; o; o >>= 1){ s1 += __shfl_xor(s1, o); s2 += __shfl_xor(s2, o); }
    if (q == 0){
        int row = ri * 16 + r;
        e1[row] = s1; e2[row] = s2;
    }
}

// ---------------- Wg -> WgF fragment layout (B-operand) ----------------
__global__ __launch_bounds__(256) void k_wgfrag(const float* __restrict__ Wg,
                                                ushort_t* __restrict__ WgF){
    int gid = blockIdx.x * 256 + threadIdx.x;
    if (gid >= (HIDD/16) * NKTX * 64) return;
    int l = gid & 63, unit = gid >> 6;
    int ci = unit / NKTX, ki = unit - ci * NKTX;
    int lm = l & 15, lh = l >> 4;
    bf16x8 pk;
    #pragma unroll
    for (int e = 0; e < 8; e++)
        ((ushort_t*)&pk)[e] = f2b(Wg[(size_t)(ki*32 + lh*8 + e) * HIDD + ci*16 + lm]);
    *(bf16x8*)(WgF + (size_t)unit * 512 + (size_t)l * 8) = pk;
}

// ---------------- Wo -> WoF fragment layout (B-operand for gemm_out) ----------------
__global__ __launch_bounds__(256) void k_wofrag(const float* __restrict__ Wo,
                                                ushort_t* __restrict__ WoF){
    int gid = blockIdx.x * 256 + threadIdx.x;
    if (gid >= (NCLSD/16) * NKTX * 64) return;
    int l = gid & 63, unit = gid >> 6;
    int ci = unit / NKTX, ki = unit - ci * NKTX;
    int lm = l & 15, lh = l >> 4;
    bf16x8 pk;
    #pragma unroll
    for (int e = 0; e < 8; e++)
        ((ushort_t*)&pk)[e] = f2b(Wo[(size_t)(ki*32 + lh*8 + e) * NCLSD + ci*16 + lm]);
    *(bf16x8*)(WoF + (size_t)unit * 512 + (size_t)l * 8) = pk;
}

// ---------------- Wh1 = X @ Wg via MFMA -> VF fragments ----------------
__global__ __launch_bounds__(512) void k_gemm_xw(const ushort_t* __restrict__ XF,
        const ushort_t* __restrict__ WgF, ushort_t* __restrict__ VF){
    int ri = blockIdx.x;
    int i0 = ri * 16;
    int w = threadIdx.x >> 6, l = threadIdx.x & 63, lm = l & 15;
    int c0 = w * 64;
    int qrow[4], vcol[4];
    calib_cd(lm, qrow, vcol);
    f32x4 acc[4] = {};
    const ushort_t* Ap = XF + (size_t)ri * NKTX * 512 + l * 8;
    const ushort_t* Bp[4];
    #pragma unroll
    for (int t = 0; t < 4; t++)
        Bp[t] = WgF + (size_t)((c0 >> 4) + t) * NKTX * 512 + l * 8;
    for (int ki = 0; ki < NKTX; ki++){
        bf16x8 af = *(const bf16x8*)(Ap + (size_t)ki * 512);
        #pragma unroll
        for (int t = 0; t < 4; t++){
            bf16x8 bf = *(const bf16x8*)(Bp[t] + (size_t)ki * 512);
            acc[t] = __builtin_amdgcn_mfma_f32_16x16x32_bf16(af, bf, acc[t], 0, 0, 0);
        }
    }
    #pragma unroll
    for (int t = 0; t < 4; t++){
        int ci = (c0 >> 4) + t;
        #pragma unroll
        for (int r = 0; r < 4; r++){
            int node = i0 + qrow[r];
            size_t vo = ((size_t)ci * NKT + (node >> 5)) * 512
                      + (size_t)(vcol[r] + ((node >> 3) & 3) * 16) * 8 + (node & 7);
            VF[vo] = f2b(acc[t][r]);
        }
    }
}

// ---------------- Wh2 = res @ Wo via MFMA; emits fp32 Wh2 + fragment VF2 ----------------
__global__ __launch_bounds__(256) void k_gemm_out(const float* __restrict__ res,
        const ushort_t* __restrict__ WoF, float* __restrict__ Wh2, ushort_t* __restrict__ VF2){
    int w = threadIdx.x >> 6, l = threadIdx.x & 63, lm = l & 15, lh = l >> 4;
    int i0 = blockIdx.x * 64 + w * 16;
    int qrow[4], vcol[4];
    calib_cd(lm, qrow, vcol);
    f32x4 acc[4] = {};
    const float* ap = res + (size_t)(i0 + lm) * HIDD + lh * 8;
    for (int k0 = 0; k0 < HIDD; k0 += 32){
        int ki = k0 >> 5;
        float4 x0 = *(const float4*)(ap + k0);
        float4 x1 = *(const float4*)(ap + k0 + 4);
        float xa[8] = {x0.x, x0.y, x0.z, x0.w, x1.x, x1.y, x1.z, x1.w};
        bf16x8 af;
        #pragma unroll
        for (int e = 0; e < 8; e++) ((ushort_t*)&af)[e] = f2b(xa[e]);
        #pragma unroll
        for (int t = 0; t < 4; t++){
            bf16x8 bf = *(const bf16x8*)(WoF + (size_t)(t * NKTX + ki) * 512 + l * 8);
            acc[t] = __builtin_amdgcn_mfma_f32_16x16x32_bf16(af, bf, acc[t], 0, 0, 0);
        }
    }
    #pragma unroll
    for (int t = 0; t < 4; t++){
        #pragma unroll
        for (int r = 0; r < 4; r++){
            int node = i0 + qrow[r], col = t*16 + vcol[r];
            float v = acc[t][r];
            Wh2[(size_t)node * NCLSD + col] = v;
            size_t vo = ((size_t)t * NKT + (node >> 5)) * 512
                      + (size_t)(vcol[r] + ((node >> 3) & 3) * 16) * 8 + (node & 7);
            VF2[vo] = f2b(v);
        }
    }
}

// ---------------- P-gen v2: reads adj directly, emits PF + byte mask + row sums ----------------
__global__ __launch_bounds__(256) void k_pgen(const int* __restrict__ adj,
        const float* __restrict__ e1, const float* __restrict__ e2,
        const float* __restrict__ e2max, ushort_t* __restrict__ PF,
        float* __restrict__ lsum, u8_t* __restrict__ mask8){
    __shared__ float e2s[NNODE];
    int ri = blockIdx.x;
    int i0 = ri * 16;
    int tid = threadIdx.x;
    int r = tid >> 4, q = tid & 15;
    for (int k = tid; k < NNODE; k += 256) e2s[k] = e2[k];
    __syncthreads();
    float e1i = e1[i0 + r];
    float M = lrelu(e1i + *e2max);   // exact upper bound (softmax shift-invariant)
    float rsum = 0.f;
    ushort_t* pfb = PF + (size_t)ri * NKT * 512;
    const int* adjp = adj + (size_t)(i0 + r) * NNODE;
    u8_t* mrow = mask8 + (size_t)(i0 + r) * (NMSK * 8);
    for (int j0 = 0; j0 < NNODE; j0 += 128){
        int j = j0 + q * 8;
        int4 a0 = *(const int4*)(adjp + j);
        int4 a1 = *(const int4*)(adjp + j + 4);
        int av[8] = {a0.x, a0.y, a0.z, a0.w, a1.x, a1.y, a1.z, a1.w};
        float4 fA = *(const float4*)&e2s[j];
        float4 fB = *(const float4*)&e2s[j + 4];
        float ea[8] = {fA.x, fA.y, fA.z, fA.w, fB.x, fB.y, fB.z, fB.w};
        bf16x8 pk;
        unsigned byte = 0;
        #pragma unroll
        for (int e = 0; e < 8; e++){
            int bit = av[e] > 0;
            byte |= (unsigned)bit << e;
            float p = bit ? __expf(lrelu(e1i + ea[e]) - M) : 0.f;
            ushort_t pb = f2b(p);
            ((ushort_t*)&pk)[e] = pb;
            rsum += b2f(pb);
        }
        mrow[j >> 3] = (u8_t)byte;
        int ki = j >> 5;
        int lh = (j >> 3) & 3;
        *(bf16x8*)(pfb + ((size_t)ki * 512 + (size_t)(r + (lh << 4)) * 8)) = pk;
    }
    #pragma unroll
    for (int o = 8; o; o >>= 1) rsum += __shfl_xor(rsum, o);
    if (q == 0) lsum[i0 + r] = rsum;
}

// ---------------- GAT1 GEMM: XCD swizzle + banked 2-deep loop (no reg copies) ----------------
__global__ __launch_bounds__(256) void k_gat1g(const ushort_t* __restrict__ PF,
        const float* __restrict__ lsum, const ushort_t* __restrict__ VF,
        float* __restrict__ res){
    int bid = blockIdx.x;
    int xcd = bid & 7;
    int k   = bid >> 3;
    int c8  = k & 7;
    int rg  = (k >> 3) * 8 + xcd;
    int tid = threadIdx.x;
    int w = tid >> 6, l = tid & 63, lm = l & 15;
    int ri = rg * 4 + w;
    int i0 = ri * 16;
    int cbase = c8 * 64;
    int qrow[4], vcol[4];
    calib_cd(lm, qrow, vcol);
    f32x4 acc[4] = {};
    const ushort_t* Ap = PF + (size_t)ri * NKT * 512 + l * 8;
    const ushort_t* Vp[4];
    #pragma unroll
    for (int t = 0; t < 4; t++)
        Vp[t] = VF + (size_t)(c8 * 4 + t) * NKT * 512 + l * 8;
    bf16x8 aA, aB, vA[4], vB[4];
    aA = *(const bf16x8*)(Ap);
    #pragma unroll
    for (int t = 0; t < 4; t++) vA[t] = *(const bf16x8*)(Vp[t]);
    for (int kt = 0; kt < NKT; kt += 2){
        size_t ob = (size_t)(kt + 1) * 512;
        aB = *(const bf16x8*)(Ap + ob);
        #pragma unroll
        for (int t = 0; t < 4; t++) vB[t] = *(const bf16x8*)(Vp[t] + ob);
        #pragma unroll
        for (int t = 0; t < 4; t++)
            acc[t] = __builtin_amdgcn_mfma_f32_16x16x32_bf16(aA, vA[t], acc[t], 0, 0, 0);
        int k2 = (kt + 2 < NKT) ? kt + 2 : 0;
        size_t oa = (size_t)k2 * 512;
        aA = *(const bf16x8*)(Ap + oa);
        #pragma unroll
        for (int t = 0; t < 4; t++) vA[t] = *(const bf16x8*)(Vp[t] + oa);
        #pragma unroll
        for (int t = 0; t < 4; t++)
            acc[t] = __builtin_amdgcn_mfma_f32_16x16x32_bf16(aB, vB[t], acc[t], 0, 0, 0);
    }
    float den[4];
    #pragma unroll
    for (int r = 0; r < 4; r++) den[r] = lsum[i0 + qrow[r]];
    #pragma unroll
    for (int t = 0; t < 4; t++){
        #pragma unroll
        for (int r = 0; r < 4; r++){
            int row = qrow[r];
            int col = cbase + t*16 + vcol[r];
            float v = acc[t][r] / den[r];
            v = v > 0.f ? v : expm1f(v);   // elu
            res[(size_t)(i0 + row) * HIDD + col] = v;
        }
    }
}

// ---------------- GAT layer 1 fallback (register P, VF layout) ----------------
__global__ __launch_bounds__(256) void k_gat1(const u64_t* __restrict__ mask,
        const float* __restrict__ e1, const float* __restrict__ e2,
        const float* __restrict__ e2max,
        const ushort_t* __restrict__ VF, float* __restrict__ res){
    __shared__ __align__(16) float e2s[NNODE];
    __shared__ u64_t msk[16][NMSK + 1];
    int bid = blockIdx.x;
    int b8 = bid & 7, a = bid >> 3;
    int ch = b8 >> 2;
    int rg = a * 4 + (b8 & 3);
    int i0 = rg * 16;
    int tid = threadIdx.x;
    int w = tid >> 6, l = tid & 63, lm = l & 15, lh = l >> 4;
    int cbase = ch * 256 + w * 64;
    int qrow[4], vcol[4];
    calib_cd(lm, qrow, vcol);
    for (int k = tid; k < NNODE; k += 256) e2s[k] = e2[k];
    for (int k = tid; k < 16 * NMSK; k += 256) msk[k / NMSK][k % NMSK] = mask[(size_t)i0 * NMSK + k];
    __syncthreads();
    float e1i = e1[i0 + lm];
    float M = lrelu(e1i + *e2max);
    float lsum = 0.f;
    f32x4 acc[4] = {};
    const ushort_t* Vp[4];
    #pragma unroll
    for (int t = 0; t < 4; t++)
        Vp[t] = VF + (size_t)((cbase >> 4) + t) * NKT * 512 + l * 8;
    bf16x8 vc[4][2], vn[4][2];
    #pragma unroll
    for (int t = 0; t < 4; t++)
        #pragma unroll
        for (int h = 0; h < 2; h++) vc[t][h] = *(const bf16x8*)(Vp[t] + h * 512);
    for (int j0 = 0; j0 < NNODE; j0 += 64){
        u64_t word = msk[lm][j0 >> 6];
        int jn = j0 + 64;
        if (jn < NNODE){
            size_t nb = (size_t)(jn >> 5) * 512;
            #pragma unroll
            for (int t = 0; t < 4; t++)
                #pragma unroll
                for (int h = 0; h < 2; h++) vn[t][h] = *(const bf16x8*)(Vp[t] + nb + h * 512);
        }
        #pragma unroll
        for (int h = 0; h < 2; h++){
            int jb = j0 + h*32 + lh*8;
            float4 fA = *(const float4*)&e2s[jb];
            float4 fB = *(const float4*)&e2s[jb + 4];
            float ea[8] = {fA.x, fA.y, fA.z, fA.w, fB.x, fB.y, fB.z, fB.w};
            int sh = h*32 + lh*8;
            bf16x8 pk;
            float ls = 0.f;
            #pragma unroll
            for (int e = 0; e < 8; e++){
                float p = ((word >> (sh + e)) & 1ull) ? __expf(lrelu(e1i + ea[e]) - M) : 0.f;
                ushort_t pb = f2b(p);
                ((ushort_t*)&pk)[e] = pb;
                ls += b2f(pb);
            }
            lsum += ls;
            #pragma unroll
            for (int t = 0; t < 4; t++)
                acc[t] = __builtin_amdgcn_mfma_f32_16x16x32_bf16(pk, vc[t][h], acc[t], 0, 0, 0);
        }
        #pragma unroll
        for (int t = 0; t < 4; t++)
            #pragma unroll
            for (int h = 0; h < 2; h++) vc[t][h] = vn[t][h];
    }
    lsum += __shfl_xor(lsum, 16);
    lsum += __shfl_xor(lsum, 32);
    #pragma unroll
    for (int t = 0; t < 4; t++){
        #pragma unroll
        for (int r = 0; r < 4; r++){
            float den = __shfl(lsum, qrow[r]);
            int row = qrow[r];
            int col = cbase + t*16 + vcol[r];
            float v = acc[t][r] / den;
            v = v > 0.f ? v : expm1f(v);
            res[(size_t)(i0 + row) * HIDD + col] = v;
        }
    }
}

// ---------------- GAT layer 2: 8-wave j-split, fragment V2, byte-mask ----------------
#define JSPAN (NNODE/8)
__global__ __launch_bounds__(512) void k_gat2(const u64_t* __restrict__ mask,
        const float* __restrict__ o1, const float* __restrict__ o2,
        const float* __restrict__ t1, const float* __restrict__ t2,
        const float* __restrict__ o2max, const float* __restrict__ t2max,
        const ushort_t* __restrict__ VF2, float* __restrict__ out2){
    __shared__ float accs[8][16][64];
    __shared__ float lsums[8][16];
    __shared__ u64_t msk[16][NMSK + 1];
    int i0 = blockIdx.x * 16;
    int tid = threadIdx.x;
    int w = tid >> 6, l = tid & 63, lm = l & 15, lh = l >> 4;
    for (int k = tid; k < 16 * NMSK; k += 512) msk[k / NMSK][k % NMSK] = mask[(size_t)i0 * NMSK + k];
    __syncthreads();
    int qrow[4], vcol[4];
    calib_cd(lm, qrow, vcol);
    int jbase = w * JSPAN;
    float o1v = o1[i0 + lm], t1v = t1[i0 + lm];
    float M = lrelu(o1v + *o2max) + lrelu(t1v + *t2max);
    float lsum = 0.f;
    f32x4 acc[4] = {};
    const float* o2p = o2 + jbase + lh * 8;
    const float* t2p = t2 + jbase + lh * 8;
    float4 oA = *(const float4*)(o2p), oB = *(const float4*)(o2p + 4);
    float4 tA = *(const float4*)(t2p), tB = *(const float4*)(t2p + 4);
    const u8_t* mrow = (const u8_t*)&msk[lm][0];
    const ushort_t* Vp[4];
    #pragma unroll
    for (int t = 0; t < 4; t++)
        Vp[t] = VF2 + (size_t)t * NKT * 512 + (size_t)(jbase >> 5) * 512 + l * 8;
    bf16x8 vcur[4], vnxt[4];
    #pragma unroll
    for (int t = 0; t < 4; t++) vcur[t] = *(const bf16x8*)(Vp[t]);

    for (int js = 0; js < JSPAN; js += 32){
        unsigned b8v = mrow[(jbase + js + lh * 8) >> 3];
        float oa[8] = {oA.x, oA.y, oA.z, oA.w, oB.x, oB.y, oB.z, oB.w};
        float ta[8] = {tA.x, tA.y, tA.z, tA.w, tB.x, tB.y, tB.z, tB.w};
        bf16x8 pk;
        float ls = 0.f;
        #pragma unroll
        for (int e = 0; e < 8; e++){
            float p = ((b8v >> e) & 1u) ?
                      __expf(lrelu(o1v + oa[e]) + lrelu(t1v + ta[e]) - M) : 0.f;
            ushort_t pb = f2b(p);
            ((ushort_t*)&pk)[e] = pb;
            ls += b2f(pb);
        }
        lsum += ls;
        int jn = js + 32;
        if (jn < JSPAN){
            oA = *(const float4*)(o2p + jn); oB = *(const float4*)(o2p + jn + 4);
            tA = *(const float4*)(t2p + jn); tB = *(const float4*)(t2p + jn + 4);
            #pragma unroll
            for (int t = 0; t < 4; t++)
                vnxt[t] = *(const bf16x8*)(Vp[t] + (size_t)(jn >> 5) * 512);
        }
        #pragma unroll
        for (int t = 0; t < 4; t++)
            acc[t] = __builtin_amdgcn_mfma_f32_16x16x32_bf16(pk, vcur[t], acc[t], 0, 0, 0);
        #pragma unroll
        for (int t = 0; t < 4; t++) vcur[t] = vnxt[t];
    }
    lsum += __shfl_xor(lsum, 16);
    lsum += __shfl_xor(lsum, 32);
    if (lh == 0) lsums[w][lm] = lsum;
    #pragma unroll
    for (int t = 0; t < 4; t++)
        #pragma unroll
        for (int r = 0; r < 4; r++)
            accs[w][qrow[r]][t*16 + vcol[r]] = acc[t][r];
    __syncthreads();
    #pragma unroll
    for (int rr = 0; rr < 2; rr++){
        int row = w * 2 + rr;
        float den = 0.f, v = 0.f;
        #pragma unroll
        for (int q = 0; q < 8; q++){ den += lsums[q][row]; v += accs[q][row][l]; }
        out2[(size_t)(i0 + row) * NCLSD + l] = v / den;
    }
}

// ---------------- row-wise log_softmax over 64 classes ----------------
__global__ void k_logsoftmax(const float* __restrict__ out2, float* __restrict__ out){
    int w = threadIdx.x >> 6, l = threadIdx.x & 63;
    int row = blockIdx.x * 4 + w;
    float v = out2[(size_t)row * NCLSD + l];
    float mx = v;
    #pragma unroll
    for (int o = 32; o; o >>= 1) mx = fmaxf(mx, __shfl_xor(mx, o));
    float ex = __expf(v - mx);
    #pragma unroll
    for (int o = 32; o; o >>= 1) ex += __shfl_xor(ex, o);
    out[(size_t)row * NCLSD + l] = v - mx - logf(ex);
}

// ---------------- launch ----------------
extern "C" void kernel_launch(void* const* d_in, const int* in_sizes, int n_in,
                              void* d_out, int out_size, void* d_ws, size_t ws_size,
                              hipStream_t stream){
    const float* X   = (const float*)d_in[0];
    const int*   adj = (const int*)d_in[1];
    const float* Wg  = (const float*)d_in[2];
    const float* ag  = (const float*)d_in[3];
    const float* Wt  = (const float*)d_in[4];
    const float* at  = (const float*)d_in[5];
    const float* Wo  = (const float*)d_in[6];
    const float* ao  = (const float*)d_in[7];
    float* out = (float*)d_out;

    char* ws = (char*)d_ws;
    size_t off = 0;
    auto take = [&](size_t n){ char* p = ws + off; off = (off + n + 255) & ~(size_t)255; return p; };
    u64_t*    maskb = (u64_t*)take((size_t)NNODE * NMSK * 8);
    ushort_t* VF    = (ushort_t*)take((size_t)HIDD * NNODE * 2);   // fragment layout Wh1
    float*    res   = (float*)take((size_t)NNODE * HIDD * 4);
    float*    Wh2   = (float*)take((size_t)NNODE * NCLSD * 4);
    ushort_t* VF2   = (ushort_t*)take((size_t)NCLSD * NNODE * 2);  // fragment layout Wh2
    ushort_t* XF    = (ushort_t*)take((size_t)NNODE * FEATD * 2);  // fragment layout X
    ushort_t* WgF   = (ushort_t*)take((size_t)FEATD * HIDD * 2);   // fragment layout Wg
    ushort_t* WoF   = (ushort_t*)take((size_t)HIDD * NCLSD * 2);   // fragment layout Wo
    float* e1v  = (float*)take(NNODE * 4);
    float* e2v  = (float*)take(NNODE * 4);
    float* t1v  = (float*)take(NNODE * 4);
    float* t2v  = (float*)take(NNODE * 4);
    float* o1v  = (float*)take(NNODE * 4);
    float* o2v  = (float*)take(NNODE * 4);
    float* wg1  = (float*)take(FEATD * 4);
    float* wg2  = (float*)take(FEATD * 4);
    float* wt1  = (float*)take(HIDD * 4);
    float* wt2  = (float*)take(HIDD * 4);
    float* scal = (float*)take(256);
    float* e2m = scal, * t2m = scal + 1, * o2m = scal + 2;
    float* out2 = Wh2;   // alias: gat2 reads only VF2/vectors

    // P fragment buffer (allocated last; only used if ws is big enough)
    size_t pbytes = (size_t)NNODE * NNODE * 2;
    bool bigws = (off + pbytes + NNODE * 4 + 4096) <= ws_size;
    ushort_t* Pbuf  = bigws ? (ushort_t*)take(pbytes) : nullptr;
    float*    lsumv = bigws ? (float*)take(NNODE * 4) : nullptr;

    // weight prep
    k_wofrag<<<dim3(((NCLSD/16)*NKTX*64 + 255)/256), dim3(256), 0, stream>>>(Wo, WoF);
    k_fold<<<dim3(FEATD/4), dim3(256), 0, stream>>>(Wg, ag, wg1, wg2, HIDD);
    k_fold<<<dim3(HIDD/4),  dim3(256), 0, stream>>>(Wt, at, wt1, wt2, HIDD);
    k_wgfrag<<<dim3(((HIDD/16)*NKTX*64 + 255)/256), dim3(256), 0, stream>>>(Wg, WgF);
    // fused X fragmentize + layer-1 scores (single X pass)
    k_xprep<<<dim3(NNODE/16), dim3(256), 0, stream>>>(X, wg1, wg2, XF, e1v, e2v);
    k_max<<<dim3(1), dim3(1024), 0, stream>>>(e2v, NNODE, e2m);
    // Wh1 via MFMA
    k_gemm_xw<<<dim3(NNODE/16), dim3(512), 0, stream>>>(XF, WgF, VF);
    // GAT layer 1 (pgen reads adj directly + emits byte mask for gat2)
    if (bigws){
        k_pgen<<<dim3(NNODE/16), dim3(256), 0, stream>>>(adj, e1v, e2v, e2m, Pbuf, lsumv, (u8_t*)maskb);
        k_gat1g<<<dim3(NNODE/64 * 8), dim3(256), 0, stream>>>(Pbuf, lsumv, VF, res);
    } else {
        k_adjmask<<<dim3(2048), dim3(256), 0, stream>>>(adj, maskb);
        k_gat1<<<dim3(NNODE/16 * 2), dim3(256), 0, stream>>>(maskb, e1v, e2v, e2m, VF, res);
    }
    // tree scores via fold
    k_rowvec2_f32<<<dim3(NNODE/4), dim3(256), 0, stream>>>(res, wt1, wt2, t1v, t2v, HIDD);
    k_max<<<dim3(1), dim3(1024), 0, stream>>>(t2v, NNODE, t2m);
    // layer-2 prep (MFMA; emits Wh2 fp32 + fragment VF2)
    k_gemm_out<<<dim3(NNODE/64), dim3(256), 0, stream>>>(res, WoF, Wh2, VF2);
    k_rowvec2_f32<<<dim3(NNODE/4), dim3(256), 0, stream>>>(Wh2, ao, ao + NCLSD, o1v, o2v, NCLSD);
    k_max<<<dim3(1), dim3(1024), 0, stream>>>(o2v, NNODE, o2m);
    // GAT layer 2 + log_softmax
    k_gat2<<<dim3(NNODE/16), dim3(512), 0, stream>>>(maskb, o1v, o2v, t1v, t2v, o2m, t2m, VF2, out2);
    k_logsoftmax<<<dim3(NNODE/4), dim3(256), 0, stream>>>(out2, out);
}

// Round 20
// 246.619 us; speedup vs baseline: 1.6561x; 1.0864x over previous
//
#include <hip/hip_runtime.h>

#define NNODE 6144
#define FEATD 512
#define HIDD  512
#define NCLSD 64
#define NMSK  (NNODE/64)   // 96 mask words per row
#define NKT   (NNODE/32)   // 192 k-tiles (node dim)
#define NKTX  (FEATD/32)   // 16 k-tiles (feature dim)
#define LALPHA 0.2f

typedef unsigned short ushort_t;
typedef unsigned char u8_t;
typedef unsigned long long u64_t;
typedef short bf16x8 __attribute__((ext_vector_type(8)));
typedef float f32x4 __attribute__((ext_vector_type(4)));

__device__ __forceinline__ float lrelu(float x){ return x > 0.f ? x : LALPHA * x; }

__device__ __forceinline__ ushort_t f2b(float x){
    union { float f; unsigned u; } v; v.f = x;
    unsigned r = v.u + 0x7fffu + ((v.u >> 16) & 1u);
    return (ushort_t)(r >> 16);
}
__device__ __forceinline__ float b2f(ushort_t u){
    union { unsigned u; float f; } v; v.u = ((unsigned)u) << 16; return v.f;
}

// Runtime C/D-layout calibration (round-8 validated)
__device__ __forceinline__ void calib_cd(int lm, int* qrow, int* vcol){
    bf16x8 ai, as;
    ushort_t vi = f2b((float)(lm + 1));
    ushort_t vs = f2b(0.03125f);
    #pragma unroll
    for (int e = 0; e < 8; e++){ ((ushort_t*)&ai)[e] = vi; ((ushort_t*)&as)[e] = vs; }
    f32x4 z = {0.f, 0.f, 0.f, 0.f};
    f32x4 d1 = __builtin_amdgcn_mfma_f32_16x16x32_bf16(ai, as, z, 0, 0, 0);
    f32x4 d2 = __builtin_amdgcn_mfma_f32_16x16x32_bf16(as, ai, z, 0, 0, 0);
    #pragma unroll
    for (int r = 0; r < 4; r++){
        qrow[r] = (int)(d1[r] + 0.5f) - 1;
        vcol[r] = (int)(d2[r] + 0.5f) - 1;
    }
}

// ---------------- adj (int32) -> bitmask (fallback path only) ----------------
__global__ void k_adjmask(const int* __restrict__ adj, u64_t* __restrict__ mask){
    int lane = threadIdx.x & 63;
    size_t wid = ((size_t)blockIdx.x * blockDim.x + threadIdx.x) >> 6;
    size_t nw = (size_t)NNODE * NNODE / 64;
    size_t stride = ((size_t)gridDim.x * blockDim.x) >> 6;
    for (size_t q = wid; q < nw; q += stride){
        int a = adj[q * 64 + lane];
        u64_t b = __ballot(a > 0);
        if (lane == 0) mask[q] = b;
    }
}

// ---------------- fold helper: out1[row]=W[row]·a[0:K], out2[row]=W[row]·a[K:2K] ----------------
__device__ __forceinline__ void fold_rows(const float* W, const float* a,
        float* out1, float* out2, int K, int blk, int tid){
    int row  = (blk * 256 + tid) >> 6;
    int lane = tid & 63;
    const float* wr = W + (size_t)row * K;
    float s1 = 0.f, s2 = 0.f;
    for (int c = lane; c < K; c += 64){ float w = wr[c]; s1 += w * a[c]; s2 += w * a[K + c]; }
    #pragma unroll
    for (int m = 32; m; m >>= 1){ s1 += __shfl_xor(s1, m); s2 += __shfl_xor(s2, m); }
    if (lane == 0){ out1[row] = s1; out2[row] = s2; }
}

// ---------------- fused prep: fold(Wg), fold(Wt), WgF, WoF (one launch) ----------------
__global__ __launch_bounds__(256) void k_prep(const float* __restrict__ Wg,
        const float* __restrict__ ag, const float* __restrict__ Wt,
        const float* __restrict__ at, const float* __restrict__ Wo,
        ushort_t* __restrict__ WgF, ushort_t* __restrict__ WoF,
        float* __restrict__ wg1, float* __restrict__ wg2,
        float* __restrict__ wt1, float* __restrict__ wt2){
    int b = blockIdx.x, tid = threadIdx.x;
    if (b < 128){                       // fold Wg·ag halves (512 rows, K=HIDD)
        fold_rows(Wg, ag, wg1, wg2, HIDD, b, tid);
    } else if (b < 256){                // fold Wt·at halves
        fold_rows(Wt, at, wt1, wt2, HIDD, b - 128, tid);
    } else if (b < 384){                // Wg -> WgF fragments
        int gid = (b - 256) * 256 + tid;
        int l = gid & 63, unit = gid >> 6;
        int ci = unit / NKTX, ki = unit - ci * NKTX;
        int lm = l & 15, lh = l >> 4;
        bf16x8 pk;
        #pragma unroll
        for (int e = 0; e < 8; e++)
            ((ushort_t*)&pk)[e] = f2b(Wg[(size_t)(ki*32 + lh*8 + e) * HIDD + ci*16 + lm]);
        *(bf16x8*)(WgF + (size_t)unit * 512 + (size_t)l * 8) = pk;
    } else {                            // Wo -> WoF fragments (16 blocks)
        int gid = (b - 384) * 256 + tid;
        if (gid >= (NCLSD/16) * NKTX * 64) return;
        int l = gid & 63, unit = gid >> 6;
        int ci = unit / NKTX, ki = unit - ci * NKTX;
        int lm = l & 15, lh = l >> 4;
        bf16x8 pk;
        #pragma unroll
        for (int e = 0; e < 8; e++)
            ((ushort_t*)&pk)[e] = f2b(Wo[(size_t)(ki*32 + lh*8 + e) * NCLSD + ci*16 + lm]);
        *(bf16x8*)(WoF + (size_t)unit * 512 + (size_t)l * 8) = pk;
    }
}

// ---------------- o1/o2 = A @ {v1,v2}  (one wave per row) ----------------
__global__ void k_rowvec2_f32(const float* __restrict__ A, const float* __restrict__ v1,
                              const float* __restrict__ v2, float* __restrict__ o1,
                              float* __restrict__ o2, int K){
    int row  = (blockIdx.x * blockDim.x + threadIdx.x) >> 6;
    int lane = threadIdx.x & 63;
    const float* r = A + (size_t)row * K;
    float s1 = 0.f, s2 = 0.f;
    for (int c = lane; c < K; c += 64){ float x = r[c]; s1 += x * v1[c]; s2 += x * v2[c]; }
    #pragma unroll
    for (int m = 32; m; m >>= 1){ s1 += __shfl_xor(s1, m); s2 += __shfl_xor(s2, m); }
    if (lane == 0){ o1[row] = s1; o2[row] = s2; }
}

// ---------------- *out = max(x[0..n))  (fallback path only) ----------------
__global__ void k_max(const float* __restrict__ x, int n, float* __restrict__ out){
    __shared__ float sm[16];
    float m = -3.0e38f;
    for (int i = threadIdx.x; i < n; i += blockDim.x) m = fmaxf(m, x[i]);
    #pragma unroll
    for (int s = 32; s; s >>= 1) m = fmaxf(m, __shfl_xor(m, s));
    if ((threadIdx.x & 63) == 0) sm[threadIdx.x >> 6] = m;
    __syncthreads();
    if (threadIdx.x == 0){
        float mm = sm[0];
        for (int i = 1; i < (int)(blockDim.x >> 6); i++) mm = fmaxf(mm, sm[i]);
        *out = mm;
    }
}

// ---------------- fused: X -> XF fragments + e1/e2 scores (single X pass) ----------------
__global__ __launch_bounds__(256) void k_xprep(const float* __restrict__ X,
        const float* __restrict__ wg1, const float* __restrict__ wg2,
        ushort_t* __restrict__ XF, float* __restrict__ e1, float* __restrict__ e2){
    __shared__ float w1s[FEATD], w2s[FEATD];
    int ri = blockIdx.x;
    int tid = threadIdx.x;
    int r = tid >> 4, q = tid & 15;
    for (int k = tid; k < FEATD; k += 256){ w1s[k] = wg1[k]; w2s[k] = wg2[k]; }
    __syncthreads();
    const float* xp = X + (size_t)(ri * 16 + r) * FEATD;
    ushort_t* xb = XF + (size_t)ri * NKTX * 512;
    float s1 = 0.f, s2 = 0.f;
    for (int j0 = 0; j0 < FEATD; j0 += 128){
        int j = j0 + q * 8;
        float4 fA = *(const float4*)(xp + j);
        float4 fB = *(const float4*)(xp + j + 4);
        float xa[8] = {fA.x, fA.y, fA.z, fA.w, fB.x, fB.y, fB.z, fB.w};
        bf16x8 pk;
        #pragma unroll
        for (int e = 0; e < 8; e++){
            ((ushort_t*)&pk)[e] = f2b(xa[e]);
            s1 += xa[e] * w1s[j + e];
            s2 += xa[e] * w2s[j + e];
        }
        int ki = j >> 5;
        int lh = (j >> 3) & 3;
        *(bf16x8*)(xb + ((size_t)ki * 512 + (size_t)(r + (lh << 4)) * 8)) = pk;
    }
    #pragma unroll
    for (int o = 8; o; o >>= 1){ s1 += __shfl_xor(s1, o); s2 += __shfl_xor(s2, o); }
    if (q == 0){
        int row = ri * 16 + r;
        e1[row] = s1; e2[row] = s2;
    }
}

// ---------------- Wh1 = X @ Wg via MFMA -> VF fragments ----------------
__global__ __launch_bounds__(512) void k_gemm_xw(const ushort_t* __restrict__ XF,
        const ushort_t* __restrict__ WgF, ushort_t* __restrict__ VF){
    int ri = blockIdx.x;
    int i0 = ri * 16;
    int w = threadIdx.x >> 6, l = threadIdx.x & 63, lm = l & 15;
    int c0 = w * 64;
    int qrow[4], vcol[4];
    calib_cd(lm, qrow, vcol);
    f32x4 acc[4] = {};
    const ushort_t* Ap = XF + (size_t)ri * NKTX * 512 + l * 8;
    const ushort_t* Bp[4];
    #pragma unroll
    for (int t = 0; t < 4; t++)
        Bp[t] = WgF + (size_t)((c0 >> 4) + t) * NKTX * 512 + l * 8;
    for (int ki = 0; ki < NKTX; ki++){
        bf16x8 af = *(const bf16x8*)(Ap + (size_t)ki * 512);
        #pragma unroll
        for (int t = 0; t < 4; t++){
            bf16x8 bf = *(const bf16x8*)(Bp[t] + (size_t)ki * 512);
            acc[t] = __builtin_amdgcn_mfma_f32_16x16x32_bf16(af, bf, acc[t], 0, 0, 0);
        }
    }
    #pragma unroll
    for (int t = 0; t < 4; t++){
        int ci = (c0 >> 4) + t;
        #pragma unroll
        for (int r = 0; r < 4; r++){
            int node = i0 + qrow[r];
            size_t vo = ((size_t)ci * NKT + (node >> 5)) * 512
                      + (size_t)(vcol[r] + ((node >> 3) & 3) * 16) * 8 + (node & 7);
            VF[vo] = f2b(acc[t][r]);
        }
    }
}

// ---------------- Wh2 = res @ Wo via MFMA; emits fp32 Wh2 + fragment VF2 ----------------
__global__ __launch_bounds__(256) void k_gemm_out(const float* __restrict__ res,
        const ushort_t* __restrict__ WoF, float* __restrict__ Wh2, ushort_t* __restrict__ VF2){
    int w = threadIdx.x >> 6, l = threadIdx.x & 63, lm = l & 15, lh = l >> 4;
    int i0 = blockIdx.x * 64 + w * 16;
    int qrow[4], vcol[4];
    calib_cd(lm, qrow, vcol);
    f32x4 acc[4] = {};
    const float* ap = res + (size_t)(i0 + lm) * HIDD + lh * 8;
    for (int k0 = 0; k0 < HIDD; k0 += 32){
        int ki = k0 >> 5;
        float4 x0 = *(const float4*)(ap + k0);
        float4 x1 = *(const float4*)(ap + k0 + 4);
        float xa[8] = {x0.x, x0.y, x0.z, x0.w, x1.x, x1.y, x1.z, x1.w};
        bf16x8 af;
        #pragma unroll
        for (int e = 0; e < 8; e++) ((ushort_t*)&af)[e] = f2b(xa[e]);
        #pragma unroll
        for (int t = 0; t < 4; t++){
            bf16x8 bf = *(const bf16x8*)(WoF + (size_t)(t * NKTX + ki) * 512 + l * 8);
            acc[t] = __builtin_amdgcn_mfma_f32_16x16x32_bf16(af, bf, acc[t], 0, 0, 0);
        }
    }
    #pragma unroll
    for (int t = 0; t < 4; t++){
        #pragma unroll
        for (int r = 0; r < 4; r++){
            int node = i0 + qrow[r], col = t*16 + vcol[r];
            float v = acc[t][r];
            Wh2[(size_t)node * NCLSD + col] = v;
            size_t vo = ((size_t)t * NKT + (node >> 5)) * 512
                      + (size_t)(vcol[r] + ((node >> 3) & 3) * 16) * 8 + (node & 7);
            VF2[vo] = f2b(v);
        }
    }
}

// ---------------- P-gen v3: reads adj, computes e2max from LDS, emits PF+mask+sums ----------------
__global__ __launch_bounds__(256) void k_pgen(const int* __restrict__ adj,
        const float* __restrict__ e1, const float* __restrict__ e2,
        ushort_t* __restrict__ PF, float* __restrict__ lsum, u8_t* __restrict__ mask8){
    __shared__ float e2s[NNODE];
    __shared__ float mred[4];
    int ri = blockIdx.x;
    int i0 = ri * 16;
    int tid = threadIdx.x;
    int r = tid >> 4, q = tid & 15;
    for (int k = tid; k < NNODE; k += 256) e2s[k] = e2[k];
    __syncthreads();
    // block-local max over e2 (deterministic, identical across blocks)
    float mx = -3.0e38f;
    for (int k = tid; k < NNODE; k += 256) mx = fmaxf(mx, e2s[k]);
    #pragma unroll
    for (int o = 32; o; o >>= 1) mx = fmaxf(mx, __shfl_xor(mx, o));
    if ((tid & 63) == 0) mred[tid >> 6] = mx;
    __syncthreads();
    float e2m = fmaxf(fmaxf(mred[0], mred[1]), fmaxf(mred[2], mred[3]));
    float e1i = e1[i0 + r];
    float M = lrelu(e1i + e2m);   // exact upper bound (softmax shift-invariant)
    float rsum = 0.f;
    ushort_t* pfb = PF + (size_t)ri * NKT * 512;
    const int* adjp = adj + (size_t)(i0 + r) * NNODE;
    u8_t* mrow = mask8 + (size_t)(i0 + r) * (NMSK * 8);
    for (int j0 = 0; j0 < NNODE; j0 += 128){
        int j = j0 + q * 8;
        int4 a0 = *(const int4*)(adjp + j);
        int4 a1 = *(const int4*)(adjp + j + 4);
        int av[8] = {a0.x, a0.y, a0.z, a0.w, a1.x, a1.y, a1.z, a1.w};
        float4 fA = *(const float4*)&e2s[j];
        float4 fB = *(const float4*)&e2s[j + 4];
        float ea[8] = {fA.x, fA.y, fA.z, fA.w, fB.x, fB.y, fB.z, fB.w};
        bf16x8 pk;
        unsigned byte = 0;
        #pragma unroll
        for (int e = 0; e < 8; e++){
            int bit = av[e] > 0;
            byte |= (unsigned)bit << e;
            float p = bit ? __expf(lrelu(e1i + ea[e]) - M) : 0.f;
            ushort_t pb = f2b(p);
            ((ushort_t*)&pk)[e] = pb;
            rsum += b2f(pb);
        }
        mrow[j >> 3] = (u8_t)byte;
        int ki = j >> 5;
        int lh = (j >> 3) & 3;
        *(bf16x8*)(pfb + ((size_t)ki * 512 + (size_t)(r + (lh << 4)) * 8)) = pk;
    }
    #pragma unroll
    for (int o = 8; o; o >>= 1) rsum += __shfl_xor(rsum, o);
    if (q == 0) lsum[i0 + r] = rsum;
}

// ---------------- GAT1 GEMM: XCD swizzle + banked 2-deep loop (no reg copies) ----------------
__global__ __launch_bounds__(256) void k_gat1g(const ushort_t* __restrict__ PF,
        const float* __restrict__ lsum, const ushort_t* __restrict__ VF,
        float* __restrict__ res){
    int bid = blockIdx.x;
    int xcd = bid & 7;
    int k   = bid >> 3;
    int c8  = k & 7;
    int rg  = (k >> 3) * 8 + xcd;
    int tid = threadIdx.x;
    int w = tid >> 6, l = tid & 63, lm = l & 15;
    int ri = rg * 4 + w;
    int i0 = ri * 16;
    int cbase = c8 * 64;
    int qrow[4], vcol[4];
    calib_cd(lm, qrow, vcol);
    f32x4 acc[4] = {};
    const ushort_t* Ap = PF + (size_t)ri * NKT * 512 + l * 8;
    const ushort_t* Vp[4];
    #pragma unroll
    for (int t = 0; t < 4; t++)
        Vp[t] = VF + (size_t)(c8 * 4 + t) * NKT * 512 + l * 8;
    bf16x8 aA, aB, vA[4], vB[4];
    aA = *(const bf16x8*)(Ap);
    #pragma unroll
    for (int t = 0; t < 4; t++) vA[t] = *(const bf16x8*)(Vp[t]);
    for (int kt = 0; kt < NKT; kt += 2){
        size_t ob = (size_t)(kt + 1) * 512;
        aB = *(const bf16x8*)(Ap + ob);
        #pragma unroll
        for (int t = 0; t < 4; t++) vB[t] = *(const bf16x8*)(Vp[t] + ob);
        #pragma unroll
        for (int t = 0; t < 4; t++)
            acc[t] = __builtin_amdgcn_mfma_f32_16x16x32_bf16(aA, vA[t], acc[t], 0, 0, 0);
        int k2 = (kt + 2 < NKT) ? kt + 2 : 0;
        size_t oa = (size_t)k2 * 512;
        aA = *(const bf16x8*)(Ap + oa);
        #pragma unroll
        for (int t = 0; t < 4; t++) vA[t] = *(const bf16x8*)(Vp[t] + oa);
        #pragma unroll
        for (int t = 0; t < 4; t++)
            acc[t] = __builtin_amdgcn_mfma_f32_16x16x32_bf16(aB, vB[t], acc[t], 0, 0, 0);
    }
    float den[4];
    #pragma unroll
    for (int r = 0; r < 4; r++) den[r] = lsum[i0 + qrow[r]];
    #pragma unroll
    for (int t = 0; t < 4; t++){
        #pragma unroll
        for (int r = 0; r < 4; r++){
            int row = qrow[r];
            int col = cbase + t*16 + vcol[r];
            float v = acc[t][r] / den[r];
            v = v > 0.f ? v : expm1f(v);   // elu
            res[(size_t)(i0 + row) * HIDD + col] = v;
        }
    }
}

// ---------------- GAT layer 1 fallback (register P, VF layout) ----------------
__global__ __launch_bounds__(256) void k_gat1(const u64_t* __restrict__ mask,
        const float* __restrict__ e1, const float* __restrict__ e2,
        const float* __restrict__ e2max,
        const ushort_t* __restrict__ VF, float* __restrict__ res){
    __shared__ __align__(16) float e2s[NNODE];
    __shared__ u64_t msk[16][NMSK + 1];
    int bid = blockIdx.x;
    int b8 = bid & 7, a = bid >> 3;
    int ch = b8 >> 2;
    int rg = a * 4 + (b8 & 3);
    int i0 = rg * 16;
    int tid = threadIdx.x;
    int w = tid >> 6, l = tid & 63, lm = l & 15, lh = l >> 4;
    int cbase = ch * 256 + w * 64;
    int qrow[4], vcol[4];
    calib_cd(lm, qrow, vcol);
    for (int k = tid; k < NNODE; k += 256) e2s[k] = e2[k];
    for (int k = tid; k < 16 * NMSK; k += 256) msk[k / NMSK][k % NMSK] = mask[(size_t)i0 * NMSK + k];
    __syncthreads();
    float e1i = e1[i0 + lm];
    float M = lrelu(e1i + *e2max);
    float lsum = 0.f;
    f32x4 acc[4] = {};
    const ushort_t* Vp[4];
    #pragma unroll
    for (int t = 0; t < 4; t++)
        Vp[t] = VF + (size_t)((cbase >> 4) + t) * NKT * 512 + l * 8;
    bf16x8 vc[4][2], vn[4][2];
    #pragma unroll
    for (int t = 0; t < 4; t++)
        #pragma unroll
        for (int h = 0; h < 2; h++) vc[t][h] = *(const bf16x8*)(Vp[t] + h * 512);
    for (int j0 = 0; j0 < NNODE; j0 += 64){
        u64_t word = msk[lm][j0 >> 6];
        int jn = j0 + 64;
        if (jn < NNODE){
            size_t nb = (size_t)(jn >> 5) * 512;
            #pragma unroll
            for (int t = 0; t < 4; t++)
                #pragma unroll
                for (int h = 0; h < 2; h++) vn[t][h] = *(const bf16x8*)(Vp[t] + nb + h * 512);
        }
        #pragma unroll
        for (int h = 0; h < 2; h++){
            int jb = j0 + h*32 + lh*8;
            float4 fA = *(const float4*)&e2s[jb];
            float4 fB = *(const float4*)&e2s[jb + 4];
            float ea[8] = {fA.x, fA.y, fA.z, fA.w, fB.x, fB.y, fB.z, fB.w};
            int sh = h*32 + lh*8;
            bf16x8 pk;
            float ls = 0.f;
            #pragma unroll
            for (int e = 0; e < 8; e++){
                float p = ((word >> (sh + e)) & 1ull) ? __expf(lrelu(e1i + ea[e]) - M) : 0.f;
                ushort_t pb = f2b(p);
                ((ushort_t*)&pk)[e] = pb;
                ls += b2f(pb);
            }
            lsum += ls;
            #pragma unroll
            for (int t = 0; t < 4; t++)
                acc[t] = __builtin_amdgcn_mfma_f32_16x16x32_bf16(pk, vc[t][h], acc[t], 0, 0, 0);
        }
        #pragma unroll
        for (int t = 0; t < 4; t++)
            #pragma unroll
            for (int h = 0; h < 2; h++) vc[t][h] = vn[t][h];
    }
    lsum += __shfl_xor(lsum, 16);
    lsum += __shfl_xor(lsum, 32);
    #pragma unroll
    for (int t = 0; t < 4; t++){
        #pragma unroll
        for (int r = 0; r < 4; r++){
            float den = __shfl(lsum, qrow[r]);
            int row = qrow[r];
            int col = cbase + t*16 + vcol[r];
            float v = acc[t][r] / den;
            v = v > 0.f ? v : expm1f(v);
            res[(size_t)(i0 + row) * HIDD + col] = v;
        }
    }
}

// ---------------- GAT layer 2 + fused log_softmax (internal maxes) ----------------
#define JSPAN (NNODE/8)
__global__ __launch_bounds__(512) void k_gat2(const u64_t* __restrict__ mask,
        const float* __restrict__ o1, const float* __restrict__ o2,
        const float* __restrict__ t1, const float* __restrict__ t2,
        const ushort_t* __restrict__ VF2, float* __restrict__ out){
    __shared__ float accs[8][16][64];
    __shared__ float lsums[8][16];
    __shared__ u64_t msk[16][NMSK + 1];
    __shared__ float mred[16];
    int i0 = blockIdx.x * 16;
    int tid = threadIdx.x;
    int w = tid >> 6, l = tid & 63, lm = l & 15, lh = l >> 4;
    for (int k = tid; k < 16 * NMSK; k += 512) msk[k / NMSK][k % NMSK] = mask[(size_t)i0 * NMSK + k];
    // block-local maxes of o2/t2 (deterministic, identical across blocks)
    float mo = -3.0e38f, mt = -3.0e38f;
    for (int k = tid; k < NNODE; k += 512){ mo = fmaxf(mo, o2[k]); mt = fmaxf(mt, t2[k]); }
    #pragma unroll
    for (int o = 32; o; o >>= 1){ mo = fmaxf(mo, __shfl_xor(mo, o)); mt = fmaxf(mt, __shfl_xor(mt, o)); }
    if (l == 0){ mred[w * 2] = mo; mred[w * 2 + 1] = mt; }
    __syncthreads();
    float o2m = -3.0e38f, t2m = -3.0e38f;
    #pragma unroll
    for (int q = 0; q < 8; q++){ o2m = fmaxf(o2m, mred[q * 2]); t2m = fmaxf(t2m, mred[q * 2 + 1]); }
    int qrow[4], vcol[4];
    calib_cd(lm, qrow, vcol);
    int jbase = w * JSPAN;
    float o1v = o1[i0 + lm], t1v = t1[i0 + lm];
    float M = lrelu(o1v + o2m) + lrelu(t1v + t2m);
    float lsum = 0.f;
    f32x4 acc[4] = {};
    const float* o2p = o2 + jbase + lh * 8;
    const float* t2p = t2 + jbase + lh * 8;
    float4 oA = *(const float4*)(o2p), oB = *(const float4*)(o2p + 4);
    float4 tA = *(const float4*)(t2p), tB = *(const float4*)(t2p + 4);
    const u8_t* mrow = (const u8_t*)&msk[lm][0];
    const ushort_t* Vp[4];
    #pragma unroll
    for (int t = 0; t < 4; t++)
        Vp[t] = VF2 + (size_t)t * NKT * 512 + (size_t)(jbase >> 5) * 512 + l * 8;
    bf16x8 vcur[4], vnxt[4];
    #pragma unroll
    for (int t = 0; t < 4; t++) vcur[t] = *(const bf16x8*)(Vp[t]);

    for (int js = 0; js < JSPAN; js += 32){
        unsigned b8v = mrow[(jbase + js + lh * 8) >> 3];
        float oa[8] = {oA.x, oA.y, oA.z, oA.w, oB.x, oB.y, oB.z, oB.w};
        float ta[8] = {tA.x, tA.y, tA.z, tA.w, tB.x, tB.y, tB.z, tB.w};
        bf16x8 pk;
        float ls = 0.f;
        #pragma unroll
        for (int e = 0; e < 8; e++){
            float p = ((b8v >> e) & 1u) ?
                      __expf(lrelu(o1v + oa[e]) + lrelu(t1v + ta[e]) - M) : 0.f;
            ushort_t pb = f2b(p);
            ((ushort_t*)&pk)[e] = pb;
            ls += b2f(pb);
        }
        lsum += ls;
        int jn = js + 32;
        if (jn < JSPAN){
            oA = *(const float4*)(o2p + jn); oB = *(const float4*)(o2p + jn + 4);
            tA = *(const float4*)(t2p + jn); tB = *(const float4*)(t2p + jn + 4);
            #pragma unroll
            for (int t = 0; t < 4; t++)
                vnxt[t] = *(const bf16x8*)(Vp[t] + (size_t)(jn >> 5) * 512);
        }
        #pragma unroll
        for (int t = 0; t < 4; t++)
            acc[t] = __builtin_amdgcn_mfma_f32_16x16x32_bf16(pk, vcur[t], acc[t], 0, 0, 0);
        #pragma unroll
        for (int t = 0; t < 4; t++) vcur[t] = vnxt[t];
    }
    lsum += __shfl_xor(lsum, 16);
    lsum += __shfl_xor(lsum, 32);
    if (lh == 0) lsums[w][lm] = lsum;
    #pragma unroll
    for (int t = 0; t < 4; t++)
        #pragma unroll
        for (int r = 0; r < 4; r++)
            accs[w][qrow[r]][t*16 + vcol[r]] = acc[t][r];
    __syncthreads();
    #pragma unroll
    for (int rr = 0; rr < 2; rr++){
        int row = w * 2 + rr;
        float den = 0.f, v = 0.f;
        #pragma unroll
        for (int q = 0; q < 8; q++){ den += lsums[q][row]; v += accs[q][row][l]; }
        float val = v / den;
        // fused log_softmax over the 64 lanes (one full class row per wave)
        float mx = val;
        #pragma unroll
        for (int o = 32; o; o >>= 1) mx = fmaxf(mx, __shfl_xor(mx, o));
        float ex = __expf(val - mx);
        #pragma unroll
        for (int o = 32; o; o >>= 1) ex += __shfl_xor(ex, o);
        out[(size_t)(i0 + row) * NCLSD + l] = val - mx - logf(ex);
    }
}

// ---------------- row-wise log_softmax (fallback path only) ----------------
__global__ void k_logsoftmax(const float* __restrict__ out2, float* __restrict__ out){
    int w = threadIdx.x >> 6, l = threadIdx.x & 63;
    int row = blockIdx.x * 4 + w;
    float v = out2[(size_t)row * NCLSD + l];
    float mx = v;
    #pragma unroll
    for (int o = 32; o; o >>= 1) mx = fmaxf(mx, __shfl_xor(mx, o));
    float ex = __expf(v - mx);
    #pragma unroll
    for (int o = 32; o; o >>= 1) ex += __shfl_xor(ex, o);
    out[(size_t)row * NCLSD + l] = v - mx - logf(ex);
}

// ---------------- launch ----------------
extern "C" void kernel_launch(void* const* d_in, const int* in_sizes, int n_in,
                              void* d_out, int out_size, void* d_ws, size_t ws_size,
                              hipStream_t stream){
    const float* X   = (const float*)d_in[0];
    const int*   adj = (const int*)d_in[1];
    const float* Wg  = (const float*)d_in[2];
    const float* ag  = (const float*)d_in[3];
    const float* Wt  = (const float*)d_in[4];
    const float* at  = (const float*)d_in[5];
    const float* Wo  = (const float*)d_in[6];
    const float* ao  = (const float*)d_in[7];
    float* out = (float*)d_out;

    char* ws = (char*)d_ws;
    size_t off = 0;
    auto take = [&](size_t n){ char* p = ws + off; off = (off + n + 255) & ~(size_t)255; return p; };
    u64_t*    maskb = (u64_t*)take((size_t)NNODE * NMSK * 8);
    ushort_t* VF    = (ushort_t*)take((size_t)HIDD * NNODE * 2);   // fragment layout Wh1
    float*    res   = (float*)take((size_t)NNODE * HIDD * 4);
    float*    Wh2   = (float*)take((size_t)NNODE * NCLSD * 4);
    ushort_t* VF2   = (ushort_t*)take((size_t)NCLSD * NNODE * 2);  // fragment layout Wh2
    ushort_t* XF    = (ushort_t*)take((size_t)NNODE * FEATD * 2);  // fragment layout X
    ushort_t* WgF   = (ushort_t*)take((size_t)FEATD * HIDD * 2);   // fragment layout Wg
    ushort_t* WoF   = (ushort_t*)take((size_t)HIDD * NCLSD * 2);   // fragment layout Wo
    float* e1v  = (float*)take(NNODE * 4);
    float* e2v  = (float*)take(NNODE * 4);
    float* t1v  = (float*)take(NNODE * 4);
    float* t2v  = (float*)take(NNODE * 4);
    float* o1v  = (float*)take(NNODE * 4);
    float* o2v  = (float*)take(NNODE * 4);
    float* wg1  = (float*)take(FEATD * 4);
    float* wg2  = (float*)take(FEATD * 4);
    float* wt1  = (float*)take(HIDD * 4);
    float* wt2  = (float*)take(HIDD * 4);
    float* scal = (float*)take(256);
    float* e2m = scal;
    float* out2 = Wh2;   // fallback alias

    // P fragment buffer (allocated last; only used if ws is big enough)
    size_t pbytes = (size_t)NNODE * NNODE * 2;
    bool bigws = (off + pbytes + NNODE * 4 + 4096) <= ws_size;
    ushort_t* Pbuf  = bigws ? (ushort_t*)take(pbytes) : nullptr;
    float*    lsumv = bigws ? (float*)take(NNODE * 4) : nullptr;

    // fused weight prep (fold Wg, fold Wt, WgF, WoF)
    k_prep<<<dim3(400), dim3(256), 0, stream>>>(Wg, ag, Wt, at, Wo, WgF, WoF, wg1, wg2, wt1, wt2);
    // fused X fragmentize + layer-1 scores (single X pass)
    k_xprep<<<dim3(NNODE/16), dim3(256), 0, stream>>>(X, wg1, wg2, XF, e1v, e2v);
    // Wh1 via MFMA
    k_gemm_xw<<<dim3(NNODE/16), dim3(512), 0, stream>>>(XF, WgF, VF);
    // GAT layer 1
    if (bigws){
        k_pgen<<<dim3(NNODE/16), dim3(256), 0, stream>>>(adj, e1v, e2v, Pbuf, lsumv, (u8_t*)maskb);
        k_gat1g<<<dim3(NNODE/64 * 8), dim3(256), 0, stream>>>(Pbuf, lsumv, VF, res);
    } else {
        k_max<<<dim3(1), dim3(1024), 0, stream>>>(e2v, NNODE, e2m);
        k_adjmask<<<dim3(2048), dim3(256), 0, stream>>>(adj, maskb);
        k_gat1<<<dim3(NNODE/16 * 2), dim3(256), 0, stream>>>(maskb, e1v, e2v, e2m, VF, res);
    }
    // tree scores via fold
    k_rowvec2_f32<<<dim3(NNODE/4), dim3(256), 0, stream>>>(res, wt1, wt2, t1v, t2v, HIDD);
    // layer-2 prep (MFMA; emits Wh2 fp32 + fragment VF2)
    k_gemm_out<<<dim3(NNODE/64), dim3(256), 0, stream>>>(res, WoF, Wh2, VF2);
    k_rowvec2_f32<<<dim3(NNODE/4), dim3(256), 0, stream>>>(Wh2, ao, ao + NCLSD, o1v, o2v, NCLSD);
    // GAT layer 2 (+internal maxes, fused log_softmax)
    k_gat2<<<dim3(NNODE/16), dim3(512), 0, stream>>>(maskb, o1v, o2v, t1v, t2v, VF2, out);
    (void)out2; (void)k_logsoftmax;
}